// Round 1
// baseline (717.899 us; speedup 1.0000x reference)
//
#include <hip/hip_runtime.h>
#include <hip/hip_bf16.h>

// Problem constants (fixed by setup_inputs)
constexpr int B_ = 64, L_ = 512, H_ = 768, T_ = 256, S_ = 128, D_ = 8;
constexpr int N_ = B_ * S_;        // 8192 nodes
constexpr int E0_ = 16 * N_;       // 131072 random edges
constexpr int NE_ = E0_ + N_;      // + self loops = 139264
constexpr float NEG_SLOPE = 0.2f;

// ---------------- token span pooling + gather selected ----------------
__global__ __launch_bounds__(256) void k_token(const float* __restrict__ features,
                                               const int* __restrict__ token_spans,
                                               const int* __restrict__ masks,
                                               const int* __restrict__ selidx,
                                               float* __restrict__ h0) {
  int n = blockIdx.x;            // node id = b*S + s
  int b = n / S_;
  int t = selidx[n];             // selected_indices flat index == n
  int st = token_spans[(b * T_ + t) * 2 + 0];
  int en = token_spans[(b * T_ + t) * 2 + 1];
  int tid = threadIdx.x;
  float a0 = 0.f, a1 = 0.f, a2 = 0.f;
  int cnt = 0;
  for (int l = st; l < en; l++) {
    if (masks[b * L_ + l] > 0) {
      cnt++;
      const float* f = features + ((size_t)b * L_ + l) * H_;
      a0 += f[tid]; a1 += f[tid + 256]; a2 += f[tid + 512];
    }
  }
  float sc = (en > 0) ? (1.0f / (float)max(cnt, 1)) : 0.0f;
  float* o = h0 + (size_t)n * H_;
  o[tid] = a0 * sc; o[tid + 256] = a1 * sc; o[tid + 512] = a2 * sc;
}

// ---------------- CSR build (edges constant across layers) ----------------
__global__ void k_count(const int* __restrict__ dst, int* __restrict__ counts, int ne) {
  int i = blockIdx.x * 256 + threadIdx.x;
  if (i < ne) atomicAdd(&counts[dst[i]], 1);
}

__global__ __launch_bounds__(1024) void k_scan(const int* __restrict__ counts,
                                               int* __restrict__ offs,
                                               int* __restrict__ cursor) {
  __shared__ int part[1024];
  int tid = threadIdx.x;
  int base = tid * 8;
  int loc[8];
  int s = 0;
  for (int i = 0; i < 8; i++) { loc[i] = s; s += counts[base + i]; }
  part[tid] = s;
  __syncthreads();
  for (int off = 1; off < 1024; off <<= 1) {
    int v = (tid >= off) ? part[tid - off] : 0;
    __syncthreads();
    part[tid] += v;
    __syncthreads();
  }
  int excl = (tid == 0) ? 0 : part[tid - 1];
  for (int i = 0; i < 8; i++) {
    int o = excl + loc[i];
    offs[base + i] = o;
    cursor[base + i] = o;
  }
  if (tid == 1023) offs[N_] = part[1023];
}

__global__ void k_scatter(const int* __restrict__ dst, int* __restrict__ cursor,
                          int* __restrict__ eidx, int ne) {
  int i = blockIdx.x * 256 + threadIdx.x;
  if (i < ne) { int p = atomicAdd(&cursor[dst[i]], 1); eidx[p] = i; }
}

// ---------------- fp32 tiled GEMM: C[M,N] = A[M,K] @ W[K,N] ----------------
// BM=64 BN=128 BK=16, 256 threads, 4x8 micro-tile
__global__ __launch_bounds__(256) void k_gemm(const float* __restrict__ A,
                                              const float* __restrict__ W,
                                              float* __restrict__ C,
                                              int M, int K, int Nn) {
  __shared__ float As[16][64];
  __shared__ float Bs[16][128];
  int tid = threadIdx.x;
  int bm = blockIdx.x * 64;
  int bn = blockIdx.y * 128;
  int tx = tid % 16;   // n-dir
  int ty = tid / 16;   // m-dir
  float c[4][8] = {};
  for (int k0 = 0; k0 < K; k0 += 16) {
    {
      int m = tid / 4;
      int kk = (tid % 4) * 4;
      float4 v = *(const float4*)&A[((size_t)(bm + m)) * K + k0 + kk];
      As[kk + 0][m] = v.x; As[kk + 1][m] = v.y; As[kk + 2][m] = v.z; As[kk + 3][m] = v.w;
    }
#pragma unroll
    for (int r = 0; r < 2; r++) {
      int t = tid + r * 256;
      int kk = t / 32;
      int n = (t % 32) * 4;
      *(float4*)&Bs[kk][n] = *(const float4*)&W[((size_t)(k0 + kk)) * Nn + bn + n];
    }
    __syncthreads();
#pragma unroll
    for (int kk = 0; kk < 16; kk++) {
      float a[4], bvals[8];
      *(float4*)a = *(const float4*)&As[kk][ty * 4];
      *(float4*)&bvals[0] = *(const float4*)&Bs[kk][tx * 8];
      *(float4*)&bvals[4] = *(const float4*)&Bs[kk][tx * 8 + 4];
#pragma unroll
      for (int i = 0; i < 4; i++)
#pragma unroll
        for (int j = 0; j < 8; j++)
          c[i][j] += a[i] * bvals[j];
    }
    __syncthreads();
  }
  for (int i = 0; i < 4; i++) {
    float4 v0 = make_float4(c[i][0], c[i][1], c[i][2], c[i][3]);
    float4 v1 = make_float4(c[i][4], c[i][5], c[i][6], c[i][7]);
    float* crow = &C[((size_t)(bm + ty * 4 + i)) * Nn + bn + tx * 8];
    *(float4*)&crow[0] = v0;
    *(float4*)&crow[4] = v1;
  }
}

// ---------------- el/er: per-node dot of z row with al / ar ----------------
__global__ __launch_bounds__(256) void k_elr(const float* __restrict__ z,
                                             const float* __restrict__ al,
                                             const float* __restrict__ ar,
                                             float* __restrict__ el,
                                             float* __restrict__ er) {
  int node = (blockIdx.x * 256 + threadIdx.x) / 64;
  int lane = threadIdx.x % 64;
  if (node >= N_) return;
  const float* zr = z + (size_t)node * H_;
  float sl = 0.f, sr = 0.f;
  for (int h = lane; h < H_; h += 64) {
    float v = zr[h];
    sl += v * al[h];
    sr += v * ar[h];
  }
  for (int off = 32; off; off >>= 1) {
    sl += __shfl_down(sl, off);
    sr += __shfl_down(sr, off);
  }
  if (lane == 0) { el[node] = sl; er[node] = sr; }
}

// ---------------- per-dst-node softmax + weighted aggregation + elu --------
__global__ __launch_bounds__(256) void k_agg(const float* __restrict__ z,
                                             const float* __restrict__ el,
                                             const float* __restrict__ er,
                                             const int* __restrict__ offs,
                                             const int* __restrict__ eidx,
                                             const int* __restrict__ src,
                                             float* __restrict__ hout) {
  int n = blockIdx.x;
  int tid = threadIdx.x;
  int o0 = offs[n], o1 = offs[n + 1];
  int deg = o1 - o0;
  float ern = er[n];
  __shared__ float red[256];

  // pass 1: max
  float lmax = -1e30f;
  for (int i = tid; i < deg; i += 256) {
    int e = eidx[o0 + i];
    float v = el[src[e]] + ern;
    v = v > 0.f ? v : NEG_SLOPE * v;
    lmax = fmaxf(lmax, v);
  }
  red[tid] = lmax; __syncthreads();
  for (int s2 = 128; s2; s2 >>= 1) { if (tid < s2) red[tid] = fmaxf(red[tid], red[tid + s2]); __syncthreads(); }
  float m = red[0]; __syncthreads();

  // pass 2: sum exp
  float lsum = 0.f;
  for (int i = tid; i < deg; i += 256) {
    int e = eidx[o0 + i];
    float v = el[src[e]] + ern;
    v = v > 0.f ? v : NEG_SLOPE * v;
    lsum += __expf(v - m);
  }
  red[tid] = lsum; __syncthreads();
  for (int s2 = 128; s2; s2 >>= 1) { if (tid < s2) red[tid] += red[tid + s2]; __syncthreads(); }
  float inv = 1.0f / red[0]; __syncthreads();

  // pass 3: weighted accumulate over edges
  float a0 = 0.f, a1 = 0.f, a2 = 0.f;
  __shared__ float ws[256];
  __shared__ int ss[256];
  for (int base = 0; base < deg; base += 256) {
    int chunk = min(256, deg - base);
    if (tid < chunk) {
      int e = eidx[o0 + base + tid];
      int s = src[e];
      float v = el[s] + ern;
      v = v > 0.f ? v : NEG_SLOPE * v;
      ws[tid] = __expf(v - m) * inv;
      ss[tid] = s;
    }
    __syncthreads();
    for (int j = 0; j < chunk; j++) {
      const float* zr = z + (size_t)ss[j] * H_;
      float w = ws[j];
      a0 += w * zr[tid];
      a1 += w * zr[tid + 256];
      a2 += w * zr[tid + 512];
    }
    __syncthreads();
  }
  float* ho = hout + (size_t)n * H_;
  ho[tid]       = a0 > 0.f ? a0 : __expf(a0) - 1.0f;
  ho[tid + 256] = a1 > 0.f ? a1 : __expf(a1) - 1.0f;
  ho[tid + 512] = a2 > 0.f ? a2 : __expf(a2) - 1.0f;
}

// ---------------- per-doc node mean (partial, atomics) ----------------
__global__ __launch_bounds__(256) void k_avg(const float* __restrict__ h,
                                             const int* __restrict__ doc_spans,
                                             float* __restrict__ avgp) {
  int b = blockIdx.x;
  int col = blockIdx.y * 256 + threadIdx.x;
  int cnt = 0;
  for (int dd = 0; dd < D_; dd++) cnt += (doc_spans[dd * 2] <= b) ? 1 : 0;
  int d = cnt - 1;
  float acc = 0.f;
  for (int s2 = 0; s2 < S_; s2++) acc += h[((size_t)b * S_ + s2) * H_ + col];
  atomicAdd(&avgp[d * H_ + col], acc);
}

// ---------------- qf: masked feature sum per doc ----------------
__global__ __launch_bounds__(256) void k_qf(const float* __restrict__ features,
                                            const int* __restrict__ masks,
                                            const int* __restrict__ segment_ids,
                                            const int* __restrict__ is_head,
                                            const int* __restrict__ doc_spans,
                                            float* __restrict__ qfp) {
  int b = blockIdx.x;
  int col = blockIdx.y * 256 + threadIdx.x;
  __shared__ float qm[L_];
  for (int l = threadIdx.x; l < L_; l += 256) {
    qm[l] = (is_head[b * L_ + l] != 2 && segment_ids[b * L_ + l] == 0 && masks[b * L_ + l] > 0) ? 1.0f : 0.0f;
  }
  __syncthreads();
  int cnt = 0;
  for (int dd = 0; dd < D_; dd++) cnt += (doc_spans[dd * 2] <= b) ? 1 : 0;
  int d = cnt - 1;
  float acc = 0.f;
  const float* f = features + (size_t)b * L_ * H_;
  for (int l = 0; l < L_; l++) {
    if (qm[l] != 0.f) acc += f[(size_t)l * H_ + col];
  }
  atomicAdd(&qfp[d * H_ + col], acc);
}

// ---------------- final: out[d] = sum_h |qf - avg| ----------------
__global__ __launch_bounds__(256) void k_final(const float* __restrict__ qfp,
                                               const float* __restrict__ avgp,
                                               const int* __restrict__ doc_spans,
                                               float* __restrict__ out) {
  __shared__ float red[256];
  int tid = threadIdx.x;
  for (int d = 0; d < D_; d++) {
    int nsent = 0;
    for (int b = 0; b < B_; b++) {
      int cnt = 0;
      for (int dd = 0; dd < D_; dd++) cnt += (doc_spans[dd * 2] <= b) ? 1 : 0;
      if (cnt - 1 == d) nsent++;
    }
    float nodecnt = fmaxf((float)(nsent * S_), 1.0f);
    float doccnt = fmaxf((float)(doc_spans[d * 2 + 1] - doc_spans[d * 2]), 1.0f);
    float acc = 0.f;
    for (int h = tid; h < H_; h += 256) {
      float q = qfp[d * H_ + h] / doccnt;
      float a = avgp[d * H_ + h] / nodecnt;
      acc += fabsf(q - a);
    }
    red[tid] = acc; __syncthreads();
    for (int s2 = 128; s2; s2 >>= 1) { if (tid < s2) red[tid] += red[tid + s2]; __syncthreads(); }
    if (tid == 0) out[d] = red[0];
    __syncthreads();
  }
}

extern "C" void kernel_launch(void* const* d_in, const int* in_sizes, int n_in,
                              void* d_out, int out_size, void* d_ws, size_t ws_size,
                              hipStream_t stream) {
  const float* features     = (const float*)d_in[0];
  const int*   token_spans  = (const int*)d_in[1];
  const int*   masks        = (const int*)d_in[2];
  const int*   selidx       = (const int*)d_in[3];
  const int*   src          = (const int*)d_in[4];
  const int*   dst          = (const int*)d_in[5];
  const int*   doc_spans    = (const int*)d_in[6];
  const int*   segment_ids  = (const int*)d_in[7];
  const int*   is_head      = (const int*)d_in[8];
  const float* Wl[3]  = {(const float*)d_in[9],  (const float*)d_in[12], (const float*)d_in[15]};
  const float* alv[3] = {(const float*)d_in[10], (const float*)d_in[13], (const float*)d_in[16]};
  const float* arv[3] = {(const float*)d_in[11], (const float*)d_in[14], (const float*)d_in[17]};
  float* out = (float*)d_out;

  char* ws = (char*)d_ws;
  size_t off = 0;
  auto alloc = [&](size_t bytes) -> void* {
    void* p = ws + off;
    off = (off + bytes + 255) & ~(size_t)255;
    return p;
  };
  float* hA     = (float*)alloc((size_t)N_ * H_ * 4);
  float* hB     = (float*)alloc((size_t)N_ * H_ * 4);
  float* el     = (float*)alloc((size_t)N_ * 4);
  float* er     = (float*)alloc((size_t)N_ * 4);
  int*   offs   = (int*)alloc((size_t)(N_ + 1) * 4);
  int*   cursor = (int*)alloc((size_t)N_ * 4);
  int*   counts = (int*)alloc((size_t)N_ * 4);
  int*   eidx   = (int*)alloc((size_t)NE_ * 4);
  float* avgp   = (float*)alloc((size_t)D_ * H_ * 4);
  float* qfp    = (float*)alloc((size_t)D_ * H_ * 4);

  // CSR build (edges constant across layers)
  hipMemsetAsync(counts, 0, (size_t)N_ * 4, stream);
  k_count<<<(NE_ + 255) / 256, 256, 0, stream>>>(dst, counts, NE_);
  k_scan<<<1, 1024, 0, stream>>>(counts, offs, cursor);
  k_scatter<<<(NE_ + 255) / 256, 256, 0, stream>>>(dst, cursor, eidx, NE_);

  // h0 = pooled selected token reps
  k_token<<<N_, 256, 0, stream>>>(features, token_spans, masks, selidx, hA);

  // 3 GAT layers: hA -> z(hB) -> hA
  for (int i = 0; i < 3; i++) {
    k_gemm<<<dim3(N_ / 64, H_ / 128), 256, 0, stream>>>(hA, Wl[i], hB, N_, H_, H_);
    k_elr<<<N_ / 4, 256, 0, stream>>>(hB, alv[i], arv[i], el, er);
    k_agg<<<N_, 256, 0, stream>>>(hB, el, er, offs, eidx, src, hA);
  }

  // doc-level reductions
  hipMemsetAsync(avgp, 0, (size_t)D_ * H_ * 4, stream);
  hipMemsetAsync(qfp, 0, (size_t)D_ * H_ * 4, stream);
  k_avg<<<dim3(B_, 3), 256, 0, stream>>>(hA, doc_spans, avgp);
  k_qf<<<dim3(B_, 3), 256, 0, stream>>>(features, masks, segment_ids, is_head, doc_spans, qfp);
  k_final<<<1, 256, 0, stream>>>(qfp, avgp, doc_spans, out);
}

// Round 2
// 406.100 us; speedup vs baseline: 1.7678x; 1.7678x over previous
//
#include <hip/hip_runtime.h>
#include <hip/hip_bf16.h>

// Problem constants (fixed by setup_inputs)
constexpr int B_ = 64, L_ = 512, H_ = 768, T_ = 256, S_ = 128, D_ = 8;
constexpr int N_ = B_ * S_;        // 8192 nodes
constexpr int E0_ = 16 * N_;       // 131072 random edges
constexpr int NE_ = E0_ + N_;      // + self loops = 139264
constexpr float NEG_SLOPE = 0.2f;

typedef __attribute__((ext_vector_type(8))) short short8v;
typedef __attribute__((ext_vector_type(4))) float f32x4;

#define GLOAD_LDS16(g, l) __builtin_amdgcn_global_load_lds( \
    (const __attribute__((address_space(1))) void*)(g), \
    (__attribute__((address_space(3))) void*)(l), 16, 0, 0)

// ---------------- token span pooling + gather selected (bf16 out) ----------
__global__ __launch_bounds__(256) void k_token(const float* __restrict__ features,
                                               const int* __restrict__ token_spans,
                                               const int* __restrict__ masks,
                                               const int* __restrict__ selidx,
                                               __hip_bfloat16* __restrict__ h0) {
  int n = blockIdx.x;            // node id = b*S + s
  int b = n / S_;
  int t = selidx[n];
  int st = token_spans[(b * T_ + t) * 2 + 0];
  int en = token_spans[(b * T_ + t) * 2 + 1];
  int tid = threadIdx.x;
  float a0 = 0.f, a1 = 0.f, a2 = 0.f;
  int cnt = 0;
  for (int l = st; l < en; l++) {
    if (masks[b * L_ + l] > 0) {
      cnt++;
      const float* f = features + ((size_t)b * L_ + l) * H_;
      a0 += f[tid]; a1 += f[tid + 256]; a2 += f[tid + 512];
    }
  }
  float sc = (en > 0) ? (1.0f / (float)max(cnt, 1)) : 0.0f;
  __hip_bfloat16* o = h0 + (size_t)n * H_;
  o[tid]       = __float2bfloat16(a0 * sc);
  o[tid + 256] = __float2bfloat16(a1 * sc);
  o[tid + 512] = __float2bfloat16(a2 * sc);
}

// ---------------- W transpose + bf16 convert: Wt[n][k] = W[k][n] -----------
__global__ __launch_bounds__(256) void k_wt(const float* __restrict__ W0,
                                            const float* __restrict__ W1,
                                            const float* __restrict__ W2,
                                            __hip_bfloat16* __restrict__ Wt) {
  const float* Ws[3] = {W0, W1, W2};
  const float* W = Ws[blockIdx.z];
  __hip_bfloat16* O = Wt + (size_t)blockIdx.z * H_ * H_;
  __shared__ float t[32][33];
  int x = threadIdx.x % 32, y = threadIdx.x / 32;   // 32x8
  int k0 = blockIdx.x * 32, n0 = blockIdx.y * 32;
  for (int i = 0; i < 32; i += 8)
    t[y + i][x] = W[(size_t)(k0 + y + i) * H_ + n0 + x];
  __syncthreads();
  for (int i = 0; i < 32; i += 8)
    O[(size_t)(n0 + y + i) * H_ + k0 + x] = __float2bfloat16(t[x][y + i]);
}

// ---------------- CSR build (edges constant across layers) ----------------
__global__ void k_count(const int* __restrict__ dst, int* __restrict__ counts, int ne) {
  int i = blockIdx.x * 256 + threadIdx.x;
  if (i < ne) atomicAdd(&counts[dst[i]], 1);
}

__global__ __launch_bounds__(1024) void k_scan(const int* __restrict__ counts,
                                               int* __restrict__ offs,
                                               int* __restrict__ cursor) {
  __shared__ int part[1024];
  int tid = threadIdx.x;
  int base = tid * 8;
  int loc[8];
  int s = 0;
  for (int i = 0; i < 8; i++) { loc[i] = s; s += counts[base + i]; }
  part[tid] = s;
  __syncthreads();
  for (int off = 1; off < 1024; off <<= 1) {
    int v = (tid >= off) ? part[tid - off] : 0;
    __syncthreads();
    part[tid] += v;
    __syncthreads();
  }
  int excl = (tid == 0) ? 0 : part[tid - 1];
  for (int i = 0; i < 8; i++) {
    int o = excl + loc[i];
    offs[base + i] = o;
    cursor[base + i] = o;
  }
  if (tid == 1023) offs[N_] = part[1023];
}

__global__ void k_scatter(const int* __restrict__ dst, int* __restrict__ cursor,
                          int* __restrict__ eidx, int ne) {
  int i = blockIdx.x * 256 + threadIdx.x;
  if (i < ne) { int p = atomicAdd(&cursor[dst[i]], 1); eidx[p] = i; }
}

// ---------------- bf16 MFMA GEMM: C[M,N] = A[M,K] @ Bt[N,K]^T --------------
// 128x128 tile, BK=32, 4 waves, each wave 64x64 (4x4 frags of 16x16x32)
__global__ __launch_bounds__(256) void k_gemm_bf16(const __hip_bfloat16* __restrict__ A,
                                                   const __hip_bfloat16* __restrict__ Bt,
                                                   float* __restrict__ C,
                                                   int M, int Nn, int K) {
  __shared__ __hip_bfloat16 As[128 * 32];
  __shared__ __hip_bfloat16 Bs[128 * 32];
  int tid = threadIdx.x;
  int bm = blockIdx.x * 128;
  int bn = blockIdx.y * 128;
  int w = tid >> 6;
  int l = tid & 63;
  int wr = w >> 1, wc = w & 1;
  int lr = l & 15;          // fragment row (A) / row of Bt tile (B's n)
  int lk = (l >> 4) * 8;    // k offset within BK=32
  f32x4 acc[4][4] = {};

  for (int k0 = 0; k0 < K; k0 += 32) {
#pragma unroll
    for (int i = 0; i < 2; i++) {
      int idx = i * 256 + tid;          // 0..511, linear in (wave,lane) order
      int row = idx >> 2;
      int ck = (idx & 3) * 8;
      GLOAD_LDS16(A + (size_t)(bm + row) * K + k0 + ck, As + (size_t)idx * 8);
    }
#pragma unroll
    for (int i = 0; i < 2; i++) {
      int idx = i * 256 + tid;
      int row = idx >> 2;
      int ck = (idx & 3) * 8;
      GLOAD_LDS16(Bt + (size_t)(bn + row) * K + k0 + ck, Bs + (size_t)idx * 8);
    }
    __syncthreads();
    short8v a_frag[4], b_frag[4];
#pragma unroll
    for (int m = 0; m < 4; m++)
      a_frag[m] = *(const short8v*)&As[(wr * 64 + m * 16 + lr) * 32 + lk];
#pragma unroll
    for (int n = 0; n < 4; n++)
      b_frag[n] = *(const short8v*)&Bs[(wc * 64 + n * 16 + lr) * 32 + lk];
#pragma unroll
    for (int m = 0; m < 4; m++)
#pragma unroll
      for (int n = 0; n < 4; n++)
        acc[m][n] = __builtin_amdgcn_mfma_f32_16x16x32_bf16(a_frag[m], b_frag[n], acc[m][n], 0, 0, 0);
    __syncthreads();
  }
  // C/D layout: col = lane&15, row = (lane>>4)*4 + r  [verified m89/m91]
#pragma unroll
  for (int m = 0; m < 4; m++) {
    int rbase = bm + wr * 64 + m * 16 + (l >> 4) * 4;
#pragma unroll
    for (int n = 0; n < 4; n++) {
      int col = bn + wc * 64 + n * 16 + lr;
#pragma unroll
      for (int r = 0; r < 4; r++)
        C[(size_t)(rbase + r) * Nn + col] = acc[m][n][r];
    }
  }
}

// ---------------- el/er: per-node dot of z row with al / ar ----------------
__global__ __launch_bounds__(256) void k_elr(const float* __restrict__ z,
                                             const float* __restrict__ al,
                                             const float* __restrict__ ar,
                                             float* __restrict__ el,
                                             float* __restrict__ er) {
  int node = (blockIdx.x * 256 + threadIdx.x) / 64;
  int lane = threadIdx.x % 64;
  if (node >= N_) return;
  const float* zr = z + (size_t)node * H_;
  float sl = 0.f, sr = 0.f;
  for (int h = lane; h < H_; h += 64) {
    float v = zr[h];
    sl += v * al[h];
    sr += v * ar[h];
  }
  for (int off = 32; off; off >>= 1) {
    sl += __shfl_down(sl, off);
    sr += __shfl_down(sr, off);
  }
  if (lane == 0) { el[node] = sl; er[node] = sr; }
}

// ---------------- per-dst-node softmax + weighted aggregation + elu --------
__global__ __launch_bounds__(256) void k_agg(const float* __restrict__ z,
                                             const float* __restrict__ el,
                                             const float* __restrict__ er,
                                             const int* __restrict__ offs,
                                             const int* __restrict__ eidx,
                                             const int* __restrict__ src,
                                             __hip_bfloat16* __restrict__ hout) {
  int n = blockIdx.x;
  int tid = threadIdx.x;
  int o0 = offs[n], o1 = offs[n + 1];
  int deg = o1 - o0;
  float ern = er[n];
  __shared__ float red[256];

  // pass 1: max
  float lmax = -1e30f;
  for (int i = tid; i < deg; i += 256) {
    int e = eidx[o0 + i];
    float v = el[src[e]] + ern;
    v = v > 0.f ? v : NEG_SLOPE * v;
    lmax = fmaxf(lmax, v);
  }
  red[tid] = lmax; __syncthreads();
  for (int s2 = 128; s2; s2 >>= 1) { if (tid < s2) red[tid] = fmaxf(red[tid], red[tid + s2]); __syncthreads(); }
  float m = red[0]; __syncthreads();

  // pass 2: sum exp
  float lsum = 0.f;
  for (int i = tid; i < deg; i += 256) {
    int e = eidx[o0 + i];
    float v = el[src[e]] + ern;
    v = v > 0.f ? v : NEG_SLOPE * v;
    lsum += __expf(v - m);
  }
  red[tid] = lsum; __syncthreads();
  for (int s2 = 128; s2; s2 >>= 1) { if (tid < s2) red[tid] += red[tid + s2]; __syncthreads(); }
  float inv = 1.0f / red[0]; __syncthreads();

  // pass 3: weighted accumulate over edges
  float a0 = 0.f, a1 = 0.f, a2 = 0.f;
  __shared__ float ws[256];
  __shared__ int ss[256];
  for (int base = 0; base < deg; base += 256) {
    int chunk = min(256, deg - base);
    if (tid < chunk) {
      int e = eidx[o0 + base + tid];
      int s = src[e];
      float v = el[s] + ern;
      v = v > 0.f ? v : NEG_SLOPE * v;
      ws[tid] = __expf(v - m) * inv;
      ss[tid] = s;
    }
    __syncthreads();
    for (int j = 0; j < chunk; j++) {
      const float* zr = z + (size_t)ss[j] * H_;
      float w = ws[j];
      a0 += w * zr[tid];
      a1 += w * zr[tid + 256];
      a2 += w * zr[tid + 512];
    }
    __syncthreads();
  }
  __hip_bfloat16* ho = hout + (size_t)n * H_;
  ho[tid]       = __float2bfloat16(a0 > 0.f ? a0 : __expf(a0) - 1.0f);
  ho[tid + 256] = __float2bfloat16(a1 > 0.f ? a1 : __expf(a1) - 1.0f);
  ho[tid + 512] = __float2bfloat16(a2 > 0.f ? a2 : __expf(a2) - 1.0f);
}

// ---------------- per-doc node mean (partial, atomics) ----------------
__global__ __launch_bounds__(256) void k_avg(const __hip_bfloat16* __restrict__ h,
                                             const int* __restrict__ doc_spans,
                                             float* __restrict__ avgp) {
  int b = blockIdx.x;
  int col = blockIdx.y * 256 + threadIdx.x;
  int cnt = 0;
  for (int dd = 0; dd < D_; dd++) cnt += (doc_spans[dd * 2] <= b) ? 1 : 0;
  int d = cnt - 1;
  float acc = 0.f;
  for (int s2 = 0; s2 < S_; s2++) acc += __bfloat162float(h[((size_t)b * S_ + s2) * H_ + col]);
  atomicAdd(&avgp[d * H_ + col], acc);
}

// ---------------- qf: masked feature sum per doc ----------------
__global__ __launch_bounds__(256) void k_qf(const float* __restrict__ features,
                                            const int* __restrict__ masks,
                                            const int* __restrict__ segment_ids,
                                            const int* __restrict__ is_head,
                                            const int* __restrict__ doc_spans,
                                            float* __restrict__ qfp) {
  int b = blockIdx.x;
  int col = blockIdx.y * 256 + threadIdx.x;
  __shared__ float qm[L_];
  for (int l = threadIdx.x; l < L_; l += 256) {
    qm[l] = (is_head[b * L_ + l] != 2 && segment_ids[b * L_ + l] == 0 && masks[b * L_ + l] > 0) ? 1.0f : 0.0f;
  }
  __syncthreads();
  int cnt = 0;
  for (int dd = 0; dd < D_; dd++) cnt += (doc_spans[dd * 2] <= b) ? 1 : 0;
  int d = cnt - 1;
  float acc = 0.f;
  const float* f = features + (size_t)b * L_ * H_;
  for (int l = 0; l < L_; l++) {
    if (qm[l] != 0.f) acc += f[(size_t)l * H_ + col];
  }
  atomicAdd(&qfp[d * H_ + col], acc);
}

// ---------------- final: out[d] = sum_h |qf - avg| ----------------
__global__ __launch_bounds__(256) void k_final(const float* __restrict__ qfp,
                                               const float* __restrict__ avgp,
                                               const int* __restrict__ doc_spans,
                                               float* __restrict__ out) {
  __shared__ float red[256];
  int tid = threadIdx.x;
  for (int d = 0; d < D_; d++) {
    int nsent = 0;
    for (int b = 0; b < B_; b++) {
      int cnt = 0;
      for (int dd = 0; dd < D_; dd++) cnt += (doc_spans[dd * 2] <= b) ? 1 : 0;
      if (cnt - 1 == d) nsent++;
    }
    float nodecnt = fmaxf((float)(nsent * S_), 1.0f);
    float doccnt = fmaxf((float)(doc_spans[d * 2 + 1] - doc_spans[d * 2]), 1.0f);
    float acc = 0.f;
    for (int h = tid; h < H_; h += 256) {
      float q = qfp[d * H_ + h] / doccnt;
      float a = avgp[d * H_ + h] / nodecnt;
      acc += fabsf(q - a);
    }
    red[tid] = acc; __syncthreads();
    for (int s2 = 128; s2; s2 >>= 1) { if (tid < s2) red[tid] += red[tid + s2]; __syncthreads(); }
    if (tid == 0) out[d] = red[0];
    __syncthreads();
  }
}

extern "C" void kernel_launch(void* const* d_in, const int* in_sizes, int n_in,
                              void* d_out, int out_size, void* d_ws, size_t ws_size,
                              hipStream_t stream) {
  const float* features     = (const float*)d_in[0];
  const int*   token_spans  = (const int*)d_in[1];
  const int*   masks        = (const int*)d_in[2];
  const int*   selidx       = (const int*)d_in[3];
  const int*   src          = (const int*)d_in[4];
  const int*   dst          = (const int*)d_in[5];
  const int*   doc_spans    = (const int*)d_in[6];
  const int*   segment_ids  = (const int*)d_in[7];
  const int*   is_head      = (const int*)d_in[8];
  const float* Wl[3]  = {(const float*)d_in[9],  (const float*)d_in[12], (const float*)d_in[15]};
  const float* alv[3] = {(const float*)d_in[10], (const float*)d_in[13], (const float*)d_in[16]};
  const float* arv[3] = {(const float*)d_in[11], (const float*)d_in[14], (const float*)d_in[17]};
  float* out = (float*)d_out;

  char* ws = (char*)d_ws;
  size_t off = 0;
  auto alloc = [&](size_t bytes) -> void* {
    void* p = ws + off;
    off = (off + bytes + 255) & ~(size_t)255;
    return p;
  };
  __hip_bfloat16* hA = (__hip_bfloat16*)alloc((size_t)N_ * H_ * 2);   // bf16 h
  float* hB          = (float*)alloc((size_t)N_ * H_ * 4);            // fp32 z
  __hip_bfloat16* Wt = (__hip_bfloat16*)alloc((size_t)3 * H_ * H_ * 2);
  float* el     = (float*)alloc((size_t)N_ * 4);
  float* er     = (float*)alloc((size_t)N_ * 4);
  int*   offs   = (int*)alloc((size_t)(N_ + 1) * 4);
  int*   cursor = (int*)alloc((size_t)N_ * 4);
  int*   counts = (int*)alloc((size_t)N_ * 4);
  int*   eidx   = (int*)alloc((size_t)NE_ * 4);
  float* avgp   = (float*)alloc((size_t)D_ * H_ * 4);
  float* qfp    = (float*)alloc((size_t)D_ * H_ * 4);

  // CSR build (edges constant across layers)
  hipMemsetAsync(counts, 0, (size_t)N_ * 4, stream);
  k_count<<<(NE_ + 255) / 256, 256, 0, stream>>>(dst, counts, NE_);
  k_scan<<<1, 1024, 0, stream>>>(counts, offs, cursor);
  k_scatter<<<(NE_ + 255) / 256, 256, 0, stream>>>(dst, cursor, eidx, NE_);

  // W transpose + bf16 convert (all 3 layers)
  k_wt<<<dim3(H_ / 32, H_ / 32, 3), 256, 0, stream>>>(Wl[0], Wl[1], Wl[2], Wt);

  // h0 = pooled selected token reps (bf16)
  k_token<<<N_, 256, 0, stream>>>(features, token_spans, masks, selidx, hA);

  // 3 GAT layers: hA(bf16) -> z(hB,f32) -> hA(bf16)
  for (int i = 0; i < 3; i++) {
    k_gemm_bf16<<<dim3(N_ / 128, H_ / 128), 256, 0, stream>>>(hA, Wt + (size_t)i * H_ * H_, hB, N_, H_, H_);
    k_elr<<<N_ / 4, 256, 0, stream>>>(hB, alv[i], arv[i], el, er);
    k_agg<<<N_, 256, 0, stream>>>(hB, el, er, offs, eidx, src, hA);
  }

  // doc-level reductions
  hipMemsetAsync(avgp, 0, (size_t)D_ * H_ * 4, stream);
  hipMemsetAsync(qfp, 0, (size_t)D_ * H_ * 4, stream);
  k_avg<<<dim3(B_, 3), 256, 0, stream>>>(hA, doc_spans, avgp);
  k_qf<<<dim3(B_, 3), 256, 0, stream>>>(features, masks, segment_ids, is_head, doc_spans, qfp);
  k_final<<<1, 256, 0, stream>>>(qfp, avgp, doc_spans, out);
}

// Round 3
// 321.174 us; speedup vs baseline: 2.2352x; 1.2644x over previous
//
#include <hip/hip_runtime.h>
#include <hip/hip_bf16.h>

// Problem constants (fixed by setup_inputs)
constexpr int B_ = 64, L_ = 512, H_ = 768, T_ = 256, S_ = 128, D_ = 8;
constexpr int N_ = B_ * S_;        // 8192 nodes
constexpr int E0_ = 16 * N_;       // 131072 random edges
constexpr int NE_ = E0_ + N_;      // + self loops = 139264
constexpr float NEG_SLOPE = 0.2f;

typedef __attribute__((ext_vector_type(8))) short short8v;
typedef __attribute__((ext_vector_type(4))) float f32x4;

#define GLOAD_LDS16(g, l) __builtin_amdgcn_global_load_lds( \
    (const __attribute__((address_space(1))) void*)(g), \
    (__attribute__((address_space(3))) void*)(l), 16, 0, 0)

__device__ __forceinline__ float bf2f(short s) {
  unsigned u = ((unsigned)(unsigned short)s) << 16;
  return __builtin_bit_cast(float, u);
}
__device__ __forceinline__ short f2bf(float f) {
  return (short)__bfloat16_as_ushort(__float2bfloat16(f));
}
__device__ __forceinline__ int docof(int b, const int* __restrict__ doc_spans) {
  int cnt = 0;
  for (int dd = 0; dd < D_; dd++) cnt += (doc_spans[dd * 2] <= b) ? 1 : 0;
  return cnt - 1;
}

// ---------------- token span pooling + gather selected (bf16 out) ----------
__global__ __launch_bounds__(192) void k_token(const float* __restrict__ features,
                                               const int* __restrict__ token_spans,
                                               const int* __restrict__ masks,
                                               const int* __restrict__ selidx,
                                               __hip_bfloat16* __restrict__ h0) {
  int n = blockIdx.x;            // node id = b*S + s
  int b = n / S_;
  int t = selidx[n];
  int st = token_spans[(b * T_ + t) * 2 + 0];
  int en = token_spans[(b * T_ + t) * 2 + 1];
  int tid = threadIdx.x;
  float4 a = make_float4(0.f, 0.f, 0.f, 0.f);
  int cnt = 0;
  for (int l = st; l < en; l++) {
    if (masks[b * L_ + l] > 0) {
      cnt++;
      float4 v = ((const float4*)(features + ((size_t)b * L_ + l) * H_))[tid];
      a.x += v.x; a.y += v.y; a.z += v.z; a.w += v.w;
    }
  }
  float sc = (en > 0) ? (1.0f / (float)max(cnt, 1)) : 0.0f;
  short4 o;
  o.x = f2bf(a.x * sc); o.y = f2bf(a.y * sc); o.z = f2bf(a.z * sc); o.w = f2bf(a.w * sc);
  ((short4*)(h0 + (size_t)n * H_))[tid] = o;
}

// ---------------- W transpose + bf16 convert: Wt[n][k] = W[k][n] -----------
__global__ __launch_bounds__(256) void k_wt(const float* __restrict__ W0,
                                            const float* __restrict__ W1,
                                            const float* __restrict__ W2,
                                            __hip_bfloat16* __restrict__ Wt) {
  const float* Ws[3] = {W0, W1, W2};
  const float* W = Ws[blockIdx.z];
  __hip_bfloat16* O = Wt + (size_t)blockIdx.z * H_ * H_;
  __shared__ float t[32][33];
  int x = threadIdx.x % 32, y = threadIdx.x / 32;   // 32x8
  int k0 = blockIdx.x * 32, n0 = blockIdx.y * 32;
  for (int i = 0; i < 32; i += 8)
    t[y + i][x] = W[(size_t)(k0 + y + i) * H_ + n0 + x];
  __syncthreads();
  for (int i = 0; i < 32; i += 8)
    O[(size_t)(n0 + y + i) * H_ + k0 + x] = __float2bfloat16(t[x][y + i]);
}

// ---------------- CSR build (edges constant across layers) ----------------
__global__ void k_count(const int* __restrict__ dst, int* __restrict__ counts, int ne) {
  int i = blockIdx.x * 256 + threadIdx.x;
  if (i < ne) atomicAdd(&counts[dst[i]], 1);
}

__global__ __launch_bounds__(1024) void k_scan(const int* __restrict__ counts,
                                               int* __restrict__ offs,
                                               int* __restrict__ cursor) {
  __shared__ int part[1024];
  int tid = threadIdx.x;
  int base = tid * 8;
  int loc[8];
  int s = 0;
  for (int i = 0; i < 8; i++) { loc[i] = s; s += counts[base + i]; }
  part[tid] = s;
  __syncthreads();
  for (int off = 1; off < 1024; off <<= 1) {
    int v = (tid >= off) ? part[tid - off] : 0;
    __syncthreads();
    part[tid] += v;
    __syncthreads();
  }
  int excl = (tid == 0) ? 0 : part[tid - 1];
  for (int i = 0; i < 8; i++) {
    int o = excl + loc[i];
    offs[base + i] = o;
    cursor[base + i] = o;
  }
  if (tid == 1023) offs[N_] = part[1023];
}

// scatter: store SOURCE NODE ID (not edge id) sorted by dst
__global__ void k_scatter(const int* __restrict__ dst, const int* __restrict__ src,
                          int* __restrict__ cursor, int* __restrict__ esrc, int ne) {
  int i = blockIdx.x * 256 + threadIdx.x;
  if (i < ne) { int p = atomicAdd(&cursor[dst[i]], 1); esrc[p] = src[i]; }
}

// ---------------- bf16 MFMA GEMM: C[M,N] = A[M,K] @ Bt[N,K]^T, bf16 out ----
// 128x128 tile, BK=32, 4 waves, each wave 64x64 (4x4 frags of 16x16x32)
__global__ __launch_bounds__(256) void k_gemm_bf16(const __hip_bfloat16* __restrict__ A,
                                                   const __hip_bfloat16* __restrict__ Bt,
                                                   __hip_bfloat16* __restrict__ C,
                                                   int M, int Nn, int K) {
  __shared__ __hip_bfloat16 As[128 * 32];
  __shared__ __hip_bfloat16 Bs[128 * 32];
  int tid = threadIdx.x;
  int bm = blockIdx.x * 128;
  int bn = blockIdx.y * 128;
  int w = tid >> 6;
  int l = tid & 63;
  int wr = w >> 1, wc = w & 1;
  int lr = l & 15;
  int lk = (l >> 4) * 8;
  f32x4 acc[4][4] = {};

  for (int k0 = 0; k0 < K; k0 += 32) {
#pragma unroll
    for (int i = 0; i < 2; i++) {
      int idx = i * 256 + tid;
      int row = idx >> 2;
      int ck = (idx & 3) * 8;
      GLOAD_LDS16(A + (size_t)(bm + row) * K + k0 + ck, As + (size_t)idx * 8);
    }
#pragma unroll
    for (int i = 0; i < 2; i++) {
      int idx = i * 256 + tid;
      int row = idx >> 2;
      int ck = (idx & 3) * 8;
      GLOAD_LDS16(Bt + (size_t)(bn + row) * K + k0 + ck, Bs + (size_t)idx * 8);
    }
    __syncthreads();
    short8v a_frag[4], b_frag[4];
#pragma unroll
    for (int m = 0; m < 4; m++)
      a_frag[m] = *(const short8v*)&As[(wr * 64 + m * 16 + lr) * 32 + lk];
#pragma unroll
    for (int n = 0; n < 4; n++)
      b_frag[n] = *(const short8v*)&Bs[(wc * 64 + n * 16 + lr) * 32 + lk];
#pragma unroll
    for (int m = 0; m < 4; m++)
#pragma unroll
      for (int n = 0; n < 4; n++)
        acc[m][n] = __builtin_amdgcn_mfma_f32_16x16x32_bf16(a_frag[m], b_frag[n], acc[m][n], 0, 0, 0);
    __syncthreads();
  }
  // C/D layout: col = lane&15, row = (lane>>4)*4 + r  [verified m89/m91]
#pragma unroll
  for (int m = 0; m < 4; m++) {
    int rbase = bm + wr * 64 + m * 16 + (l >> 4) * 4;
#pragma unroll
    for (int n = 0; n < 4; n++) {
      int col = bn + wc * 64 + n * 16 + lr;
#pragma unroll
      for (int r = 0; r < 4; r++)
        C[(size_t)(rbase + r) * Nn + col] = __float2bfloat16(acc[m][n][r]);
    }
  }
}

// ---------------- el/er: per-node dot of z row with al / ar ----------------
__global__ __launch_bounds__(256) void k_elr(const __hip_bfloat16* __restrict__ z,
                                             const float* __restrict__ al,
                                             const float* __restrict__ ar,
                                             float* __restrict__ el,
                                             float* __restrict__ er) {
  int node = blockIdx.x * 4 + (threadIdx.x >> 6);
  int lane = threadIdx.x & 63;
  const short4* zr = (const short4*)(z + (size_t)node * H_);
  float sl = 0.f, sr = 0.f;
#pragma unroll
  for (int i = 0; i < 3; i++) {
    short4 v = zr[lane + i * 64];
    int col = (lane + i * 64) * 4;
    float4 a = *(const float4*)&al[col];
    float4 r = *(const float4*)&ar[col];
    float f0 = bf2f(v.x), f1 = bf2f(v.y), f2 = bf2f(v.z), f3 = bf2f(v.w);
    sl += f0 * a.x + f1 * a.y + f2 * a.z + f3 * a.w;
    sr += f0 * r.x + f1 * r.y + f2 * r.z + f3 * r.w;
  }
  for (int off = 32; off; off >>= 1) {
    sl += __shfl_xor(sl, off);
    sr += __shfl_xor(sr, off);
  }
  if (lane == 0) { el[node] = sl; er[node] = sr; }
}

// ---------------- wave-per-dst-node softmax + weighted agg + elu ----------
__global__ __launch_bounds__(256) void k_agg(const __hip_bfloat16* __restrict__ z,
                                             const float* __restrict__ el,
                                             const float* __restrict__ er,
                                             const int* __restrict__ offs,
                                             const int* __restrict__ esrc,
                                             __hip_bfloat16* __restrict__ hout) {
  int wv = threadIdx.x >> 6, lane = threadIdx.x & 63;
  int n = blockIdx.x * 4 + wv;
  int o0 = offs[n];
  int deg = offs[n + 1] - o0;
  float ern = er[n];
  float acc[12] = {};

  if (deg <= 64) {
    // single-chunk fast path: one random load per edge total
    float w_ = 0.f; int s_ = 0;
    if (lane < deg) {
      s_ = esrc[o0 + lane];
      float v = el[s_] + ern;
      w_ = v > 0.f ? v : NEG_SLOPE * v;
    } else {
      w_ = -1e30f;
    }
    float m = w_;
    for (int off = 32; off; off >>= 1) m = fmaxf(m, __shfl_xor(m, off));
    float ex = (lane < deg) ? __expf(w_ - m) : 0.f;
    float sum = ex;
    for (int off = 32; off; off >>= 1) sum += __shfl_xor(sum, off);
    w_ = ex / sum;
    for (int j = 0; j < deg; j++) {
      float wj = __shfl(w_, j);
      int sj = __shfl(s_, j);
      const short4* zr = (const short4*)(z + (size_t)sj * H_);
#pragma unroll
      for (int i = 0; i < 3; i++) {
        short4 v = zr[lane + i * 64];
        acc[i * 4 + 0] += wj * bf2f(v.x);
        acc[i * 4 + 1] += wj * bf2f(v.y);
        acc[i * 4 + 2] += wj * bf2f(v.z);
        acc[i * 4 + 3] += wj * bf2f(v.w);
      }
    }
  } else {
    // generic chunked path
    float lmax = -1e30f;
    for (int i = lane; i < deg; i += 64) {
      float v = el[esrc[o0 + i]] + ern;
      v = v > 0.f ? v : NEG_SLOPE * v;
      lmax = fmaxf(lmax, v);
    }
    for (int off = 32; off; off >>= 1) lmax = fmaxf(lmax, __shfl_xor(lmax, off));
    float lsum = 0.f;
    for (int i = lane; i < deg; i += 64) {
      float v = el[esrc[o0 + i]] + ern;
      v = v > 0.f ? v : NEG_SLOPE * v;
      lsum += __expf(v - lmax);
    }
    for (int off = 32; off; off >>= 1) lsum += __shfl_xor(lsum, off);
    float inv = 1.0f / lsum;
    for (int base = 0; base < deg; base += 64) {
      int chunk = min(64, deg - base);
      float w_ = 0.f; int s_ = 0;
      if (lane < chunk) {
        s_ = esrc[o0 + base + lane];
        float v = el[s_] + ern;
        v = v > 0.f ? v : NEG_SLOPE * v;
        w_ = __expf(v - lmax) * inv;
      }
      for (int j = 0; j < chunk; j++) {
        float wj = __shfl(w_, j);
        int sj = __shfl(s_, j);
        const short4* zr = (const short4*)(z + (size_t)sj * H_);
#pragma unroll
        for (int i = 0; i < 3; i++) {
          short4 v = zr[lane + i * 64];
          acc[i * 4 + 0] += wj * bf2f(v.x);
          acc[i * 4 + 1] += wj * bf2f(v.y);
          acc[i * 4 + 2] += wj * bf2f(v.z);
          acc[i * 4 + 3] += wj * bf2f(v.w);
        }
      }
    }
  }

  short4* ho = (short4*)(hout + (size_t)n * H_);
#pragma unroll
  for (int i = 0; i < 3; i++) {
    float e0 = acc[i * 4 + 0]; e0 = e0 > 0.f ? e0 : __expf(e0) - 1.f;
    float e1 = acc[i * 4 + 1]; e1 = e1 > 0.f ? e1 : __expf(e1) - 1.f;
    float e2 = acc[i * 4 + 2]; e2 = e2 > 0.f ? e2 : __expf(e2) - 1.f;
    float e3 = acc[i * 4 + 3]; e3 = e3 > 0.f ? e3 : __expf(e3) - 1.f;
    short4 o; o.x = f2bf(e0); o.y = f2bf(e1); o.z = f2bf(e2); o.w = f2bf(e3);
    ho[lane + i * 64] = o;
  }
}

// ---------------- per-doc node mean: grid (B, 8), 16 sents/block ----------
__global__ __launch_bounds__(192) void k_avg(const __hip_bfloat16* __restrict__ h,
                                             const int* __restrict__ doc_spans,
                                             float* __restrict__ avgp) {
  int b = blockIdx.x;
  int s0 = blockIdx.y * 16;
  int tid = threadIdx.x;
  float4 a = make_float4(0.f, 0.f, 0.f, 0.f);
  for (int i = 0; i < 16; i++) {
    short4 v = ((const short4*)(h + ((size_t)(b * S_ + s0 + i)) * H_))[tid];
    a.x += bf2f(v.x); a.y += bf2f(v.y); a.z += bf2f(v.z); a.w += bf2f(v.w);
  }
  int d = docof(b, doc_spans);
  atomicAdd(&avgp[d * H_ + tid * 4 + 0], a.x);
  atomicAdd(&avgp[d * H_ + tid * 4 + 1], a.y);
  atomicAdd(&avgp[d * H_ + tid * 4 + 2], a.z);
  atomicAdd(&avgp[d * H_ + tid * 4 + 3], a.w);
}

// ---------------- qf: masked feature sum per doc: grid (B, 32) ------------
__global__ __launch_bounds__(192) void k_qf(const float* __restrict__ features,
                                            const int* __restrict__ masks,
                                            const int* __restrict__ segment_ids,
                                            const int* __restrict__ is_head,
                                            const int* __restrict__ doc_spans,
                                            float* __restrict__ qfp) {
  int b = blockIdx.x;
  int l0 = blockIdx.y * 16;
  int tid = threadIdx.x;
  __shared__ float qm[16];
  if (tid < 16) {
    int l = l0 + tid;
    qm[tid] = (is_head[b * L_ + l] != 2 && segment_ids[b * L_ + l] == 0 && masks[b * L_ + l] > 0) ? 1.0f : 0.0f;
  }
  __syncthreads();
  float4 a = make_float4(0.f, 0.f, 0.f, 0.f);
  for (int i = 0; i < 16; i++) {
    if (qm[i] != 0.f) {
      float4 v = ((const float4*)(features + ((size_t)b * L_ + l0 + i) * H_))[tid];
      a.x += v.x; a.y += v.y; a.z += v.z; a.w += v.w;
    }
  }
  int d = docof(b, doc_spans);
  atomicAdd(&qfp[d * H_ + tid * 4 + 0], a.x);
  atomicAdd(&qfp[d * H_ + tid * 4 + 1], a.y);
  atomicAdd(&qfp[d * H_ + tid * 4 + 2], a.z);
  atomicAdd(&qfp[d * H_ + tid * 4 + 3], a.w);
}

// ---------------- final: out[d] = sum_h |qf - avg| ----------------
__global__ __launch_bounds__(256) void k_final(const float* __restrict__ qfp,
                                               const float* __restrict__ avgp,
                                               const int* __restrict__ doc_spans,
                                               float* __restrict__ out) {
  __shared__ float red[256];
  int tid = threadIdx.x;
  for (int d = 0; d < D_; d++) {
    int nsent = 0;
    for (int b = 0; b < B_; b++) {
      if (docof(b, doc_spans) == d) nsent++;
    }
    float nodecnt = fmaxf((float)(nsent * S_), 1.0f);
    float doccnt = fmaxf((float)(doc_spans[d * 2 + 1] - doc_spans[d * 2]), 1.0f);
    float acc = 0.f;
    for (int h = tid; h < H_; h += 256) {
      float q = qfp[d * H_ + h] / doccnt;
      float a = avgp[d * H_ + h] / nodecnt;
      acc += fabsf(q - a);
    }
    red[tid] = acc; __syncthreads();
    for (int s2 = 128; s2; s2 >>= 1) { if (tid < s2) red[tid] += red[tid + s2]; __syncthreads(); }
    if (tid == 0) out[d] = red[0];
    __syncthreads();
  }
}

extern "C" void kernel_launch(void* const* d_in, const int* in_sizes, int n_in,
                              void* d_out, int out_size, void* d_ws, size_t ws_size,
                              hipStream_t stream) {
  const float* features     = (const float*)d_in[0];
  const int*   token_spans  = (const int*)d_in[1];
  const int*   masks        = (const int*)d_in[2];
  const int*   selidx       = (const int*)d_in[3];
  const int*   src          = (const int*)d_in[4];
  const int*   dst          = (const int*)d_in[5];
  const int*   doc_spans    = (const int*)d_in[6];
  const int*   segment_ids  = (const int*)d_in[7];
  const int*   is_head      = (const int*)d_in[8];
  const float* Wl[3]  = {(const float*)d_in[9],  (const float*)d_in[12], (const float*)d_in[15]};
  const float* alv[3] = {(const float*)d_in[10], (const float*)d_in[13], (const float*)d_in[16]};
  const float* arv[3] = {(const float*)d_in[11], (const float*)d_in[14], (const float*)d_in[17]};
  float* out = (float*)d_out;

  char* ws = (char*)d_ws;
  size_t off = 0;
  auto alloc = [&](size_t bytes) -> void* {
    void* p = ws + off;
    off = (off + bytes + 255) & ~(size_t)255;
    return p;
  };
  __hip_bfloat16* hA = (__hip_bfloat16*)alloc((size_t)N_ * H_ * 2);   // bf16 h
  __hip_bfloat16* hB = (__hip_bfloat16*)alloc((size_t)N_ * H_ * 2);   // bf16 z
  __hip_bfloat16* Wt = (__hip_bfloat16*)alloc((size_t)3 * H_ * H_ * 2);
  float* el     = (float*)alloc((size_t)N_ * 4);
  float* er     = (float*)alloc((size_t)N_ * 4);
  int*   offs   = (int*)alloc((size_t)(N_ + 1) * 4);
  int*   cursor = (int*)alloc((size_t)N_ * 4);
  int*   counts = (int*)alloc((size_t)N_ * 4);
  int*   esrc   = (int*)alloc((size_t)NE_ * 4);
  float* avgp   = (float*)alloc((size_t)D_ * H_ * 4);
  float* qfp    = (float*)alloc((size_t)D_ * H_ * 4);

  // CSR build (edges constant across layers)
  hipMemsetAsync(counts, 0, (size_t)N_ * 4, stream);
  k_count<<<(NE_ + 255) / 256, 256, 0, stream>>>(dst, counts, NE_);
  k_scan<<<1, 1024, 0, stream>>>(counts, offs, cursor);
  k_scatter<<<(NE_ + 255) / 256, 256, 0, stream>>>(dst, src, cursor, esrc, NE_);

  // W transpose + bf16 convert (all 3 layers)
  k_wt<<<dim3(H_ / 32, H_ / 32, 3), 256, 0, stream>>>(Wl[0], Wl[1], Wl[2], Wt);

  // h0 = pooled selected token reps (bf16)
  k_token<<<N_, 192, 0, stream>>>(features, token_spans, masks, selidx, hA);

  // 3 GAT layers: hA(bf16) -> z(hB,bf16) -> hA(bf16)
  for (int i = 0; i < 3; i++) {
    k_gemm_bf16<<<dim3(N_ / 128, H_ / 128), 256, 0, stream>>>(hA, Wt + (size_t)i * H_ * H_, hB, N_, H_, H_);
    k_elr<<<N_ / 4, 256, 0, stream>>>(hB, alv[i], arv[i], el, er);
    k_agg<<<N_ / 4, 256, 0, stream>>>(hB, el, er, offs, esrc, hA);
  }

  // doc-level reductions
  hipMemsetAsync(avgp, 0, (size_t)D_ * H_ * 4, stream);
  hipMemsetAsync(qfp, 0, (size_t)D_ * H_ * 4, stream);
  k_avg<<<dim3(B_, 8), 192, 0, stream>>>(hA, doc_spans, avgp);
  k_qf<<<dim3(B_, 32), 192, 0, stream>>>(features, masks, segment_ids, is_head, doc_spans, qfp);
  k_final<<<1, 256, 0, stream>>>(qfp, avgp, doc_spans, out);
}

// Round 4
// 274.022 us; speedup vs baseline: 2.6199x; 1.1721x over previous
//
#include <hip/hip_runtime.h>
#include <hip/hip_bf16.h>

// Problem constants (fixed by setup_inputs)
constexpr int B_ = 64, L_ = 512, H_ = 768, T_ = 256, S_ = 128, D_ = 8;
constexpr int N_ = B_ * S_;        // 8192 nodes
constexpr int E0_ = 16 * N_;       // 131072 random edges
constexpr int NE_ = E0_ + N_;      // + self loops = 139264
constexpr float NEG_SLOPE = 0.2f;

typedef __attribute__((ext_vector_type(8))) short short8v;
typedef __attribute__((ext_vector_type(4))) float f32x4;

#define GLOAD_LDS16(g, l) __builtin_amdgcn_global_load_lds( \
    (const __attribute__((address_space(1))) void*)(g), \
    (__attribute__((address_space(3))) void*)(l), 16, 0, 0)

__device__ __forceinline__ float bf2f(short s) {
  unsigned u = ((unsigned)(unsigned short)s) << 16;
  return __builtin_bit_cast(float, u);
}
__device__ __forceinline__ short f2bf(float f) {
  return (short)__bfloat16_as_ushort(__float2bfloat16(f));
}
__device__ __forceinline__ int docof(int b, const int* __restrict__ doc_spans) {
  int cnt = 0;
  for (int dd = 0; dd < D_; dd++) cnt += (doc_spans[dd * 2] <= b) ? 1 : 0;
  return cnt - 1;
}

// ---------------- token span pooling + gather selected (bf16 out) ----------
__global__ __launch_bounds__(192) void k_token(const float* __restrict__ features,
                                               const int* __restrict__ token_spans,
                                               const int* __restrict__ masks,
                                               const int* __restrict__ selidx,
                                               __hip_bfloat16* __restrict__ h0) {
  int n = blockIdx.x;            // node id = b*S + s
  int b = n / S_;
  int t = selidx[n];
  int st = token_spans[(b * T_ + t) * 2 + 0];
  int en = token_spans[(b * T_ + t) * 2 + 1];
  int tid = threadIdx.x;
  float4 a = make_float4(0.f, 0.f, 0.f, 0.f);
  int cnt = 0;
  for (int l = st; l < en; l++) {
    if (masks[b * L_ + l] > 0) {
      cnt++;
      float4 v = ((const float4*)(features + ((size_t)b * L_ + l) * H_))[tid];
      a.x += v.x; a.y += v.y; a.z += v.z; a.w += v.w;
    }
  }
  float sc = (en > 0) ? (1.0f / (float)max(cnt, 1)) : 0.0f;
  short4 o;
  o.x = f2bf(a.x * sc); o.y = f2bf(a.y * sc); o.z = f2bf(a.z * sc); o.w = f2bf(a.w * sc);
  ((short4*)(h0 + (size_t)n * H_))[tid] = o;
}

// ---------------- W transpose + bf16 convert: Wt[n][k] = W[k][n] -----------
__global__ __launch_bounds__(256) void k_wt(const float* __restrict__ W0,
                                            const float* __restrict__ W1,
                                            const float* __restrict__ W2,
                                            __hip_bfloat16* __restrict__ Wt) {
  const float* Ws[3] = {W0, W1, W2};
  const float* W = Ws[blockIdx.z];
  __hip_bfloat16* O = Wt + (size_t)blockIdx.z * H_ * H_;
  __shared__ float t[32][33];
  int x = threadIdx.x % 32, y = threadIdx.x / 32;   // 32x8
  int k0 = blockIdx.x * 32, n0 = blockIdx.y * 32;
  for (int i = 0; i < 32; i += 8)
    t[y + i][x] = W[(size_t)(k0 + y + i) * H_ + n0 + x];
  __syncthreads();
  for (int i = 0; i < 32; i += 8)
    O[(size_t)(n0 + y + i) * H_ + k0 + x] = __float2bfloat16(t[x][y + i]);
}

// ---------------- CSR build (edges constant across layers) ----------------
__global__ void k_count(const int* __restrict__ dst, int* __restrict__ counts, int ne) {
  int i = blockIdx.x * 256 + threadIdx.x;
  if (i < ne) atomicAdd(&counts[dst[i]], 1);
}

__global__ __launch_bounds__(1024) void k_scan(const int* __restrict__ counts,
                                               int* __restrict__ offs,
                                               int* __restrict__ cursor) {
  __shared__ int part[1024];
  int tid = threadIdx.x;
  int base = tid * 8;
  int loc[8];
  int s = 0;
  for (int i = 0; i < 8; i++) { loc[i] = s; s += counts[base + i]; }
  part[tid] = s;
  __syncthreads();
  for (int off = 1; off < 1024; off <<= 1) {
    int v = (tid >= off) ? part[tid - off] : 0;
    __syncthreads();
    part[tid] += v;
    __syncthreads();
  }
  int excl = (tid == 0) ? 0 : part[tid - 1];
  for (int i = 0; i < 8; i++) {
    int o = excl + loc[i];
    offs[base + i] = o;
    cursor[base + i] = o;
  }
  if (tid == 1023) offs[N_] = part[1023];
}

// scatter: store SOURCE NODE ID (not edge id) sorted by dst
__global__ void k_scatter(const int* __restrict__ dst, const int* __restrict__ src,
                          int* __restrict__ cursor, int* __restrict__ esrc, int ne) {
  int i = blockIdx.x * 256 + threadIdx.x;
  if (i < ne) { int p = atomicAdd(&cursor[dst[i]], 1); esrc[p] = src[i]; }
}

// ---------------- bf16 MFMA GEMM: C[M,N] = A[M,K] @ Bt[N,K]^T, bf16 out ----
// 128x128 tile, BK=32, 4 waves, each wave 64x64 (4x4 frags of 16x16x32)
__global__ __launch_bounds__(256) void k_gemm_bf16(const __hip_bfloat16* __restrict__ A,
                                                   const __hip_bfloat16* __restrict__ Bt,
                                                   __hip_bfloat16* __restrict__ C,
                                                   int M, int Nn, int K) {
  __shared__ __hip_bfloat16 As[128 * 32];
  __shared__ __hip_bfloat16 Bs[128 * 32];
  int tid = threadIdx.x;
  int bm = blockIdx.x * 128;
  int bn = blockIdx.y * 128;
  int w = tid >> 6;
  int l = tid & 63;
  int wr = w >> 1, wc = w & 1;
  int lr = l & 15;
  int lk = (l >> 4) * 8;
  f32x4 acc[4][4] = {};

  for (int k0 = 0; k0 < K; k0 += 32) {
#pragma unroll
    for (int i = 0; i < 2; i++) {
      int idx = i * 256 + tid;
      int row = idx >> 2;
      int ck = (idx & 3) * 8;
      GLOAD_LDS16(A + (size_t)(bm + row) * K + k0 + ck, As + (size_t)idx * 8);
    }
#pragma unroll
    for (int i = 0; i < 2; i++) {
      int idx = i * 256 + tid;
      int row = idx >> 2;
      int ck = (idx & 3) * 8;
      GLOAD_LDS16(Bt + (size_t)(bn + row) * K + k0 + ck, Bs + (size_t)idx * 8);
    }
    __syncthreads();
    short8v a_frag[4], b_frag[4];
#pragma unroll
    for (int m = 0; m < 4; m++)
      a_frag[m] = *(const short8v*)&As[(wr * 64 + m * 16 + lr) * 32 + lk];
#pragma unroll
    for (int n = 0; n < 4; n++)
      b_frag[n] = *(const short8v*)&Bs[(wc * 64 + n * 16 + lr) * 32 + lk];
#pragma unroll
    for (int m = 0; m < 4; m++)
#pragma unroll
      for (int n = 0; n < 4; n++)
        acc[m][n] = __builtin_amdgcn_mfma_f32_16x16x32_bf16(a_frag[m], b_frag[n], acc[m][n], 0, 0, 0);
    __syncthreads();
  }
  // C/D layout: col = lane&15, row = (lane>>4)*4 + r  [verified m89/m91]
#pragma unroll
  for (int m = 0; m < 4; m++) {
    int rbase = bm + wr * 64 + m * 16 + (l >> 4) * 4;
#pragma unroll
    for (int n = 0; n < 4; n++) {
      int col = bn + wc * 64 + n * 16 + lr;
#pragma unroll
      for (int r = 0; r < 4; r++)
        C[(size_t)(rbase + r) * Nn + col] = __float2bfloat16(acc[m][n][r]);
    }
  }
}

// ---------------- el/er: per-node dot of z row with al / ar ----------------
__global__ __launch_bounds__(256) void k_elr(const __hip_bfloat16* __restrict__ z,
                                             const float* __restrict__ al,
                                             const float* __restrict__ ar,
                                             float* __restrict__ el,
                                             float* __restrict__ er) {
  int node = blockIdx.x * 4 + (threadIdx.x >> 6);
  int lane = threadIdx.x & 63;
  const short4* zr = (const short4*)(z + (size_t)node * H_);
  float sl = 0.f, sr = 0.f;
#pragma unroll
  for (int i = 0; i < 3; i++) {
    short4 v = zr[lane + i * 64];
    int col = (lane + i * 64) * 4;
    float4 a = *(const float4*)&al[col];
    float4 r = *(const float4*)&ar[col];
    float f0 = bf2f(v.x), f1 = bf2f(v.y), f2 = bf2f(v.z), f3 = bf2f(v.w);
    sl += f0 * a.x + f1 * a.y + f2 * a.z + f3 * a.w;
    sr += f0 * r.x + f1 * r.y + f2 * r.z + f3 * r.w;
  }
  for (int off = 32; off; off >>= 1) {
    sl += __shfl_xor(sl, off);
    sr += __shfl_xor(sr, off);
  }
  if (lane == 0) { el[node] = sl; er[node] = sr; }
}

// ---------------- wave-per-dst-node softmax + weighted agg + elu ----------
__global__ __launch_bounds__(256) void k_agg(const __hip_bfloat16* __restrict__ z,
                                             const float* __restrict__ el,
                                             const float* __restrict__ er,
                                             const int* __restrict__ offs,
                                             const int* __restrict__ esrc,
                                             __hip_bfloat16* __restrict__ hout) {
  int wv = threadIdx.x >> 6, lane = threadIdx.x & 63;
  int n = blockIdx.x * 4 + wv;
  int o0 = offs[n];
  int deg = offs[n + 1] - o0;
  float ern = er[n];
  float acc[12] = {};

  if (deg <= 64) {
    // single-chunk fast path: one random load per edge total
    float w_ = 0.f; int s_ = 0;
    if (lane < deg) {
      s_ = esrc[o0 + lane];
      float v = el[s_] + ern;
      w_ = v > 0.f ? v : NEG_SLOPE * v;
    } else {
      w_ = -1e30f;
    }
    float m = w_;
    for (int off = 32; off; off >>= 1) m = fmaxf(m, __shfl_xor(m, off));
    float ex = (lane < deg) ? __expf(w_ - m) : 0.f;
    float sum = ex;
    for (int off = 32; off; off >>= 1) sum += __shfl_xor(sum, off);
    w_ = ex / sum;
    for (int j = 0; j < deg; j++) {
      float wj = __shfl(w_, j);
      int sj = __shfl(s_, j);
      const short4* zr = (const short4*)(z + (size_t)sj * H_);
#pragma unroll
      for (int i = 0; i < 3; i++) {
        short4 v = zr[lane + i * 64];
        acc[i * 4 + 0] += wj * bf2f(v.x);
        acc[i * 4 + 1] += wj * bf2f(v.y);
        acc[i * 4 + 2] += wj * bf2f(v.z);
        acc[i * 4 + 3] += wj * bf2f(v.w);
      }
    }
  } else {
    // generic chunked path
    float lmax = -1e30f;
    for (int i = lane; i < deg; i += 64) {
      float v = el[esrc[o0 + i]] + ern;
      v = v > 0.f ? v : NEG_SLOPE * v;
      lmax = fmaxf(lmax, v);
    }
    for (int off = 32; off; off >>= 1) lmax = fmaxf(lmax, __shfl_xor(lmax, off));
    float lsum = 0.f;
    for (int i = lane; i < deg; i += 64) {
      float v = el[esrc[o0 + i]] + ern;
      v = v > 0.f ? v : NEG_SLOPE * v;
      lsum += __expf(v - lmax);
    }
    for (int off = 32; off; off >>= 1) lsum += __shfl_xor(lsum, off);
    float inv = 1.0f / lsum;
    for (int base = 0; base < deg; base += 64) {
      int chunk = min(64, deg - base);
      float w_ = 0.f; int s_ = 0;
      if (lane < chunk) {
        s_ = esrc[o0 + base + lane];
        float v = el[s_] + ern;
        v = v > 0.f ? v : NEG_SLOPE * v;
        w_ = __expf(v - lmax) * inv;
      }
      for (int j = 0; j < chunk; j++) {
        float wj = __shfl(w_, j);
        int sj = __shfl(s_, j);
        const short4* zr = (const short4*)(z + (size_t)sj * H_);
#pragma unroll
        for (int i = 0; i < 3; i++) {
          short4 v = zr[lane + i * 64];
          acc[i * 4 + 0] += wj * bf2f(v.x);
          acc[i * 4 + 1] += wj * bf2f(v.y);
          acc[i * 4 + 2] += wj * bf2f(v.z);
          acc[i * 4 + 3] += wj * bf2f(v.w);
        }
      }
    }
  }

  short4* ho = (short4*)(hout + (size_t)n * H_);
#pragma unroll
  for (int i = 0; i < 3; i++) {
    float e0 = acc[i * 4 + 0]; e0 = e0 > 0.f ? e0 : __expf(e0) - 1.f;
    float e1 = acc[i * 4 + 1]; e1 = e1 > 0.f ? e1 : __expf(e1) - 1.f;
    float e2 = acc[i * 4 + 2]; e2 = e2 > 0.f ? e2 : __expf(e2) - 1.f;
    float e3 = acc[i * 4 + 3]; e3 = e3 > 0.f ? e3 : __expf(e3) - 1.f;
    short4 o; o.x = f2bf(e0); o.y = f2bf(e1); o.z = f2bf(e2); o.w = f2bf(e3);
    ho[lane + i * 64] = o;
  }
}

// ---------------- per-doc node mean: grid (B, 8), 16 sents/block ----------
__global__ __launch_bounds__(192) void k_avg(const __hip_bfloat16* __restrict__ h,
                                             const int* __restrict__ doc_spans,
                                             float* __restrict__ avgp) {
  int b = blockIdx.x;
  int s0 = blockIdx.y * 16;
  int tid = threadIdx.x;
  float4 a = make_float4(0.f, 0.f, 0.f, 0.f);
  for (int i = 0; i < 16; i++) {
    short4 v = ((const short4*)(h + ((size_t)(b * S_ + s0 + i)) * H_))[tid];
    a.x += bf2f(v.x); a.y += bf2f(v.y); a.z += bf2f(v.z); a.w += bf2f(v.w);
  }
  int d = docof(b, doc_spans);
  atomicAdd(&avgp[d * H_ + tid * 4 + 0], a.x);
  atomicAdd(&avgp[d * H_ + tid * 4 + 1], a.y);
  atomicAdd(&avgp[d * H_ + tid * 4 + 2], a.z);
  atomicAdd(&avgp[d * H_ + tid * 4 + 3], a.w);
}

// ---------------- qf: masked feature sum per doc: grid (B, 32) ------------
__global__ __launch_bounds__(192) void k_qf(const float* __restrict__ features,
                                            const int* __restrict__ masks,
                                            const int* __restrict__ segment_ids,
                                            const int* __restrict__ is_head,
                                            const int* __restrict__ doc_spans,
                                            float* __restrict__ qfp) {
  int b = blockIdx.x;
  int l0 = blockIdx.y * 16;
  int tid = threadIdx.x;
  __shared__ float qm[16];
  if (tid < 16) {
    int l = l0 + tid;
    qm[tid] = (is_head[b * L_ + l] != 2 && segment_ids[b * L_ + l] == 0 && masks[b * L_ + l] > 0) ? 1.0f : 0.0f;
  }
  __syncthreads();
  float4 a = make_float4(0.f, 0.f, 0.f, 0.f);
  for (int i = 0; i < 16; i++) {
    if (qm[i] != 0.f) {
      float4 v = ((const float4*)(features + ((size_t)b * L_ + l0 + i) * H_))[tid];
      a.x += v.x; a.y += v.y; a.z += v.z; a.w += v.w;
    }
  }
  int d = docof(b, doc_spans);
  atomicAdd(&qfp[d * H_ + tid * 4 + 0], a.x);
  atomicAdd(&qfp[d * H_ + tid * 4 + 1], a.y);
  atomicAdd(&qfp[d * H_ + tid * 4 + 2], a.z);
  atomicAdd(&qfp[d * H_ + tid * 4 + 3], a.w);
}

// ---------------- final: out[d] = sum_h |qf/doccnt - avg/nodecnt| ----------
// one wave per doc; doc_spans staged in LDS once (was: 4096 serial global loads)
__global__ __launch_bounds__(512) void k_final(const float* __restrict__ qfp,
                                               const float* __restrict__ avgp,
                                               const int* __restrict__ doc_spans,
                                               float* __restrict__ out) {
  __shared__ int ds[D_ * 2];
  int tid = threadIdx.x;
  if (tid < D_ * 2) ds[tid] = doc_spans[tid];
  __syncthreads();
  int d = tid >> 6, lane = tid & 63;
  int nsent = 0;
  for (int b = 0; b < B_; b++) {
    int cnt = 0;
#pragma unroll
    for (int dd = 0; dd < D_; dd++) cnt += (ds[dd * 2] <= b) ? 1 : 0;
    nsent += ((cnt - 1) == d) ? 1 : 0;
  }
  float inv_node = 1.0f / fmaxf((float)nsent * (float)S_, 1.0f);
  float inv_doc  = 1.0f / fmaxf((float)(ds[d * 2 + 1] - ds[d * 2]), 1.0f);
  float acc = 0.f;
  for (int h = lane; h < H_; h += 64)
    acc += fabsf(qfp[d * H_ + h] * inv_doc - avgp[d * H_ + h] * inv_node);
  for (int off = 32; off; off >>= 1) acc += __shfl_xor(acc, off);
  if (lane == 0) out[d] = acc;
}

extern "C" void kernel_launch(void* const* d_in, const int* in_sizes, int n_in,
                              void* d_out, int out_size, void* d_ws, size_t ws_size,
                              hipStream_t stream) {
  const float* features     = (const float*)d_in[0];
  const int*   token_spans  = (const int*)d_in[1];
  const int*   masks        = (const int*)d_in[2];
  const int*   selidx       = (const int*)d_in[3];
  const int*   src          = (const int*)d_in[4];
  const int*   dst          = (const int*)d_in[5];
  const int*   doc_spans    = (const int*)d_in[6];
  const int*   segment_ids  = (const int*)d_in[7];
  const int*   is_head      = (const int*)d_in[8];
  const float* Wl[3]  = {(const float*)d_in[9],  (const float*)d_in[12], (const float*)d_in[15]};
  const float* alv[3] = {(const float*)d_in[10], (const float*)d_in[13], (const float*)d_in[16]};
  const float* arv[3] = {(const float*)d_in[11], (const float*)d_in[14], (const float*)d_in[17]};
  float* out = (float*)d_out;

  char* ws = (char*)d_ws;
  size_t off = 0;
  auto alloc = [&](size_t bytes) -> void* {
    void* p = ws + off;
    off = (off + bytes + 255) & ~(size_t)255;
    return p;
  };
  __hip_bfloat16* hA = (__hip_bfloat16*)alloc((size_t)N_ * H_ * 2);   // bf16 h
  __hip_bfloat16* hB = (__hip_bfloat16*)alloc((size_t)N_ * H_ * 2);   // bf16 z
  __hip_bfloat16* Wt = (__hip_bfloat16*)alloc((size_t)3 * H_ * H_ * 2);
  float* el     = (float*)alloc((size_t)N_ * 4);
  float* er     = (float*)alloc((size_t)N_ * 4);
  int*   offs   = (int*)alloc((size_t)(N_ + 1) * 4);
  int*   cursor = (int*)alloc((size_t)N_ * 4);
  int*   counts = (int*)alloc((size_t)N_ * 4);
  int*   esrc   = (int*)alloc((size_t)NE_ * 4);
  float* avgp   = (float*)alloc((size_t)2 * D_ * H_ * 4);  // avgp | qfp contiguous
  float* qfp    = avgp + (size_t)D_ * H_;

  // zero accumulators (single fill for both) + CSR counts
  hipMemsetAsync(avgp, 0, (size_t)2 * D_ * H_ * 4, stream);
  hipMemsetAsync(counts, 0, (size_t)N_ * 4, stream);

  // CSR build (edges constant across layers)
  k_count<<<(NE_ + 255) / 256, 256, 0, stream>>>(dst, counts, NE_);
  k_scan<<<1, 1024, 0, stream>>>(counts, offs, cursor);
  k_scatter<<<(NE_ + 255) / 256, 256, 0, stream>>>(dst, src, cursor, esrc, NE_);

  // W transpose + bf16 convert (all 3 layers)
  k_wt<<<dim3(H_ / 32, H_ / 32, 3), 256, 0, stream>>>(Wl[0], Wl[1], Wl[2], Wt);

  // h0 = pooled selected token reps (bf16)
  k_token<<<N_, 192, 0, stream>>>(features, token_spans, masks, selidx, hA);

  // 3 GAT layers: hA(bf16) -> z(hB,bf16) -> hA(bf16)
  for (int i = 0; i < 3; i++) {
    k_gemm_bf16<<<dim3(N_ / 128, H_ / 128), 256, 0, stream>>>(hA, Wt + (size_t)i * H_ * H_, hB, N_, H_, H_);
    k_elr<<<N_ / 4, 256, 0, stream>>>(hB, alv[i], arv[i], el, er);
    k_agg<<<N_ / 4, 256, 0, stream>>>(hB, el, er, offs, esrc, hA);
  }

  // doc-level reductions
  k_avg<<<dim3(B_, 8), 192, 0, stream>>>(hA, doc_spans, avgp);
  k_qf<<<dim3(B_, 32), 192, 0, stream>>>(features, masks, segment_ids, is_head, doc_spans, qfp);
  k_final<<<1, 512, 0, stream>>>(qfp, avgp, doc_spans, out);
}

// Round 5
// 265.791 us; speedup vs baseline: 2.7010x; 1.0310x over previous
//
#include <hip/hip_runtime.h>
#include <hip/hip_bf16.h>

// Problem constants (fixed by setup_inputs)
constexpr int B_ = 64, L_ = 512, H_ = 768, T_ = 256, S_ = 128, D_ = 8;
constexpr int N_ = B_ * S_;        // 8192 nodes
constexpr int E0_ = 16 * N_;       // 131072 random edges
constexpr int NE_ = E0_ + N_;      // + self loops = 139264
constexpr float NEG_SLOPE = 0.2f;

typedef __attribute__((ext_vector_type(8))) short short8v;
typedef __attribute__((ext_vector_type(4))) float f32x4;

#define GLOAD_LDS16(g, l) __builtin_amdgcn_global_load_lds( \
    (const __attribute__((address_space(1))) void*)(g), \
    (__attribute__((address_space(3))) void*)(l), 16, 0, 0)

__device__ __forceinline__ float bf2f(short s) {
  unsigned u = ((unsigned)(unsigned short)s) << 16;
  return __builtin_bit_cast(float, u);
}
__device__ __forceinline__ short f2bf(float f) {
  return (short)__bfloat16_as_ushort(__float2bfloat16(f));
}
__device__ __forceinline__ int docof(int b, const int* __restrict__ doc_spans) {
  int cnt = 0;
  for (int dd = 0; dd < D_; dd++) cnt += (doc_spans[dd * 2] <= b) ? 1 : 0;
  return cnt - 1;
}

// ---------------- token span pooling + gather selected (bf16 out) ----------
__global__ __launch_bounds__(192) void k_token(const float* __restrict__ features,
                                               const int* __restrict__ token_spans,
                                               const int* __restrict__ masks,
                                               const int* __restrict__ selidx,
                                               __hip_bfloat16* __restrict__ h0) {
  int n = blockIdx.x;            // node id = b*S + s
  int b = n / S_;
  int t = selidx[n];
  int st = token_spans[(b * T_ + t) * 2 + 0];
  int en = token_spans[(b * T_ + t) * 2 + 1];
  int tid = threadIdx.x;
  float4 a = make_float4(0.f, 0.f, 0.f, 0.f);
  int cnt = 0;
  for (int l = st; l < en; l++) {
    if (masks[b * L_ + l] > 0) {
      cnt++;
      float4 v = ((const float4*)(features + ((size_t)b * L_ + l) * H_))[tid];
      a.x += v.x; a.y += v.y; a.z += v.z; a.w += v.w;
    }
  }
  float sc = (en > 0) ? (1.0f / (float)max(cnt, 1)) : 0.0f;
  short4 o;
  o.x = f2bf(a.x * sc); o.y = f2bf(a.y * sc); o.z = f2bf(a.z * sc); o.w = f2bf(a.w * sc);
  ((short4*)(h0 + (size_t)n * H_))[tid] = o;
}

// ---------------- W transpose + bf16 convert: Wt[n][k] = W[k][n] -----------
__global__ __launch_bounds__(256) void k_wt(const float* __restrict__ W0,
                                            const float* __restrict__ W1,
                                            const float* __restrict__ W2,
                                            __hip_bfloat16* __restrict__ Wt) {
  const float* Ws[3] = {W0, W1, W2};
  const float* W = Ws[blockIdx.z];
  __hip_bfloat16* O = Wt + (size_t)blockIdx.z * H_ * H_;
  __shared__ float t[32][33];
  int x = threadIdx.x % 32, y = threadIdx.x / 32;   // 32x8
  int k0 = blockIdx.x * 32, n0 = blockIdx.y * 32;
  for (int i = 0; i < 32; i += 8)
    t[y + i][x] = W[(size_t)(k0 + y + i) * H_ + n0 + x];
  __syncthreads();
  for (int i = 0; i < 32; i += 8)
    O[(size_t)(n0 + y + i) * H_ + k0 + x] = __float2bfloat16(t[x][y + i]);
}

// ---------------- CSR build (edges constant across layers) ----------------
__global__ void k_count(const int* __restrict__ dst, int* __restrict__ counts, int ne) {
  int i = blockIdx.x * 256 + threadIdx.x;
  if (i < ne) atomicAdd(&counts[dst[i]], 1);
}

__global__ __launch_bounds__(1024) void k_scan(const int* __restrict__ counts,
                                               int* __restrict__ offs,
                                               int* __restrict__ cursor) {
  __shared__ int part[1024];
  int tid = threadIdx.x;
  int base = tid * 8;
  int loc[8];
  int s = 0;
  for (int i = 0; i < 8; i++) { loc[i] = s; s += counts[base + i]; }
  part[tid] = s;
  __syncthreads();
  for (int off = 1; off < 1024; off <<= 1) {
    int v = (tid >= off) ? part[tid - off] : 0;
    __syncthreads();
    part[tid] += v;
    __syncthreads();
  }
  int excl = (tid == 0) ? 0 : part[tid - 1];
  for (int i = 0; i < 8; i++) {
    int o = excl + loc[i];
    offs[base + i] = o;
    cursor[base + i] = o;
  }
  if (tid == 1023) offs[N_] = part[1023];
}

// scatter: store SOURCE NODE ID (not edge id) sorted by dst
__global__ void k_scatter(const int* __restrict__ dst, const int* __restrict__ src,
                          int* __restrict__ cursor, int* __restrict__ esrc, int ne) {
  int i = blockIdx.x * 256 + threadIdx.x;
  if (i < ne) { int p = atomicAdd(&cursor[dst[i]], 1); esrc[p] = src[i]; }
}

// ------ bf16 MFMA GEMM + fused el/er partial dots: C = A @ Bt^T ----------
// 128x128 tile, BK=32, 4 waves, each wave 64x64 (4x4 frags of 16x16x32)
// epilogue: el[row] += sum_cols z*al, er[row] += sum_cols z*ar (atomics)
__global__ __launch_bounds__(256) void k_gemm_bf16(const __hip_bfloat16* __restrict__ A,
                                                   const __hip_bfloat16* __restrict__ Bt,
                                                   __hip_bfloat16* __restrict__ C,
                                                   const float* __restrict__ al,
                                                   const float* __restrict__ ar,
                                                   float* __restrict__ el,
                                                   float* __restrict__ er,
                                                   int M, int Nn, int K) {
  __shared__ __hip_bfloat16 As[128 * 32];
  __shared__ __hip_bfloat16 Bs[128 * 32];
  int tid = threadIdx.x;
  int bm = blockIdx.x * 128;
  int bn = blockIdx.y * 128;
  int w = tid >> 6;
  int l = tid & 63;
  int wr = w >> 1, wc = w & 1;
  int lr = l & 15;
  int lk = (l >> 4) * 8;
  f32x4 acc[4][4] = {};

  for (int k0 = 0; k0 < K; k0 += 32) {
#pragma unroll
    for (int i = 0; i < 2; i++) {
      int idx = i * 256 + tid;
      int row = idx >> 2;
      int ck = (idx & 3) * 8;
      GLOAD_LDS16(A + (size_t)(bm + row) * K + k0 + ck, As + (size_t)idx * 8);
    }
#pragma unroll
    for (int i = 0; i < 2; i++) {
      int idx = i * 256 + tid;
      int row = idx >> 2;
      int ck = (idx & 3) * 8;
      GLOAD_LDS16(Bt + (size_t)(bn + row) * K + k0 + ck, Bs + (size_t)idx * 8);
    }
    __syncthreads();
    short8v a_frag[4], b_frag[4];
#pragma unroll
    for (int m = 0; m < 4; m++)
      a_frag[m] = *(const short8v*)&As[(wr * 64 + m * 16 + lr) * 32 + lk];
#pragma unroll
    for (int n = 0; n < 4; n++)
      b_frag[n] = *(const short8v*)&Bs[(wc * 64 + n * 16 + lr) * 32 + lk];
#pragma unroll
    for (int m = 0; m < 4; m++)
#pragma unroll
      for (int n = 0; n < 4; n++)
        acc[m][n] = __builtin_amdgcn_mfma_f32_16x16x32_bf16(a_frag[m], b_frag[n], acc[m][n], 0, 0, 0);
    __syncthreads();
  }
  // per-lane al/ar for this block's columns: col = bn + wc*64 + n*16 + lr
  float alv[4], arv[4];
#pragma unroll
  for (int n = 0; n < 4; n++) {
    int col = bn + wc * 64 + n * 16 + lr;
    alv[n] = al[col]; arv[n] = ar[col];
  }
  // C/D layout: col = lane&15, row = (lane>>4)*4 + r  [verified m89/m91]
#pragma unroll
  for (int m = 0; m < 4; m++) {
    int rbase = bm + wr * 64 + m * 16 + (l >> 4) * 4;
#pragma unroll
    for (int n = 0; n < 4; n++) {
      int col = bn + wc * 64 + n * 16 + lr;
#pragma unroll
      for (int r = 0; r < 4; r++)
        C[(size_t)(rbase + r) * Nn + col] = __float2bfloat16(acc[m][n][r]);
    }
    // fused el/er partials: reduce over the 16 lanes of each row group
#pragma unroll
    for (int r = 0; r < 4; r++) {
      float pel = 0.f, per_ = 0.f;
#pragma unroll
      for (int n = 0; n < 4; n++) {
        pel  += acc[m][n][r] * alv[n];
        per_ += acc[m][n][r] * arv[n];
      }
#pragma unroll
      for (int off2 = 1; off2 < 16; off2 <<= 1) {
        pel  += __shfl_xor(pel,  off2);
        per_ += __shfl_xor(per_, off2);
      }
      if (lr == 0) {
        atomicAdd(&el[rbase + r], pel);
        atomicAdd(&er[rbase + r], per_);
      }
    }
  }
}

// ---------------- wave-per-dst-node softmax + weighted agg + elu ----------
__global__ __launch_bounds__(256) void k_agg(const __hip_bfloat16* __restrict__ z,
                                             const float* __restrict__ el,
                                             const float* __restrict__ er,
                                             const int* __restrict__ offs,
                                             const int* __restrict__ esrc,
                                             __hip_bfloat16* __restrict__ hout) {
  int wv = threadIdx.x >> 6, lane = threadIdx.x & 63;
  int n = blockIdx.x * 4 + wv;
  int o0 = offs[n];
  int deg = offs[n + 1] - o0;
  float ern = er[n];
  float acc[12] = {};

  if (deg <= 64) {
    // single-chunk fast path: one random load per edge total
    float w_ = 0.f; int s_ = 0;
    if (lane < deg) {
      s_ = esrc[o0 + lane];
      float v = el[s_] + ern;
      w_ = v > 0.f ? v : NEG_SLOPE * v;
    } else {
      w_ = -1e30f;
    }
    float m = w_;
    for (int off = 32; off; off >>= 1) m = fmaxf(m, __shfl_xor(m, off));
    float ex = (lane < deg) ? __expf(w_ - m) : 0.f;
    float sum = ex;
    for (int off = 32; off; off >>= 1) sum += __shfl_xor(sum, off);
    w_ = ex / sum;
    for (int j = 0; j < deg; j++) {
      float wj = __shfl(w_, j);
      int sj = __shfl(s_, j);
      const short4* zr = (const short4*)(z + (size_t)sj * H_);
#pragma unroll
      for (int i = 0; i < 3; i++) {
        short4 v = zr[lane + i * 64];
        acc[i * 4 + 0] += wj * bf2f(v.x);
        acc[i * 4 + 1] += wj * bf2f(v.y);
        acc[i * 4 + 2] += wj * bf2f(v.z);
        acc[i * 4 + 3] += wj * bf2f(v.w);
      }
    }
  } else {
    // generic chunked path
    float lmax = -1e30f;
    for (int i = lane; i < deg; i += 64) {
      float v = el[esrc[o0 + i]] + ern;
      v = v > 0.f ? v : NEG_SLOPE * v;
      lmax = fmaxf(lmax, v);
    }
    for (int off = 32; off; off >>= 1) lmax = fmaxf(lmax, __shfl_xor(lmax, off));
    float lsum = 0.f;
    for (int i = lane; i < deg; i += 64) {
      float v = el[esrc[o0 + i]] + ern;
      v = v > 0.f ? v : NEG_SLOPE * v;
      lsum += __expf(v - lmax);
    }
    for (int off = 32; off; off >>= 1) lsum += __shfl_xor(lsum, off);
    float inv = 1.0f / lsum;
    for (int base = 0; base < deg; base += 64) {
      int chunk = min(64, deg - base);
      float w_ = 0.f; int s_ = 0;
      if (lane < chunk) {
        s_ = esrc[o0 + base + lane];
        float v = el[s_] + ern;
        v = v > 0.f ? v : NEG_SLOPE * v;
        w_ = __expf(v - lmax) * inv;
      }
      for (int j = 0; j < chunk; j++) {
        float wj = __shfl(w_, j);
        int sj = __shfl(s_, j);
        const short4* zr = (const short4*)(z + (size_t)sj * H_);
#pragma unroll
        for (int i = 0; i < 3; i++) {
          short4 v = zr[lane + i * 64];
          acc[i * 4 + 0] += wj * bf2f(v.x);
          acc[i * 4 + 1] += wj * bf2f(v.y);
          acc[i * 4 + 2] += wj * bf2f(v.z);
          acc[i * 4 + 3] += wj * bf2f(v.w);
        }
      }
    }
  }

  short4* ho = (short4*)(hout + (size_t)n * H_);
#pragma unroll
  for (int i = 0; i < 3; i++) {
    float e0 = acc[i * 4 + 0]; e0 = e0 > 0.f ? e0 : __expf(e0) - 1.f;
    float e1 = acc[i * 4 + 1]; e1 = e1 > 0.f ? e1 : __expf(e1) - 1.f;
    float e2 = acc[i * 4 + 2]; e2 = e2 > 0.f ? e2 : __expf(e2) - 1.f;
    float e3 = acc[i * 4 + 3]; e3 = e3 > 0.f ? e3 : __expf(e3) - 1.f;
    short4 o; o.x = f2bf(e0); o.y = f2bf(e1); o.z = f2bf(e2); o.w = f2bf(e3);
    ho[lane + i * 64] = o;
  }
}

// ---------------- per-doc node mean: grid (B, 8), 16 sents/block ----------
__global__ __launch_bounds__(192) void k_avg(const __hip_bfloat16* __restrict__ h,
                                             const int* __restrict__ doc_spans,
                                             float* __restrict__ avgp) {
  int b = blockIdx.x;
  int s0 = blockIdx.y * 16;
  int tid = threadIdx.x;
  float4 a = make_float4(0.f, 0.f, 0.f, 0.f);
  for (int i = 0; i < 16; i++) {
    short4 v = ((const short4*)(h + ((size_t)(b * S_ + s0 + i)) * H_))[tid];
    a.x += bf2f(v.x); a.y += bf2f(v.y); a.z += bf2f(v.z); a.w += bf2f(v.w);
  }
  int d = docof(b, doc_spans);
  atomicAdd(&avgp[d * H_ + tid * 4 + 0], a.x);
  atomicAdd(&avgp[d * H_ + tid * 4 + 1], a.y);
  atomicAdd(&avgp[d * H_ + tid * 4 + 2], a.z);
  atomicAdd(&avgp[d * H_ + tid * 4 + 3], a.w);
}

// ---------------- qf: masked feature sum per doc: grid (B, 32) ------------
__global__ __launch_bounds__(192) void k_qf(const float* __restrict__ features,
                                            const int* __restrict__ masks,
                                            const int* __restrict__ segment_ids,
                                            const int* __restrict__ is_head,
                                            const int* __restrict__ doc_spans,
                                            float* __restrict__ qfp) {
  int b = blockIdx.x;
  int l0 = blockIdx.y * 16;
  int tid = threadIdx.x;
  __shared__ float qm[16];
  if (tid < 16) {
    int l = l0 + tid;
    qm[tid] = (is_head[b * L_ + l] != 2 && segment_ids[b * L_ + l] == 0 && masks[b * L_ + l] > 0) ? 1.0f : 0.0f;
  }
  __syncthreads();
  float4 a = make_float4(0.f, 0.f, 0.f, 0.f);
  for (int i = 0; i < 16; i++) {
    if (qm[i] != 0.f) {
      float4 v = ((const float4*)(features + ((size_t)b * L_ + l0 + i) * H_))[tid];
      a.x += v.x; a.y += v.y; a.z += v.z; a.w += v.w;
    }
  }
  int d = docof(b, doc_spans);
  atomicAdd(&qfp[d * H_ + tid * 4 + 0], a.x);
  atomicAdd(&qfp[d * H_ + tid * 4 + 1], a.y);
  atomicAdd(&qfp[d * H_ + tid * 4 + 2], a.z);
  atomicAdd(&qfp[d * H_ + tid * 4 + 3], a.w);
}

// ---------------- final: out[d] = sum_h |qf/doccnt - avg/nodecnt| ----------
__global__ __launch_bounds__(512) void k_final(const float* __restrict__ qfp,
                                               const float* __restrict__ avgp,
                                               const int* __restrict__ doc_spans,
                                               float* __restrict__ out) {
  __shared__ int ds[D_ * 2];
  int tid = threadIdx.x;
  if (tid < D_ * 2) ds[tid] = doc_spans[tid];
  __syncthreads();
  int d = tid >> 6, lane = tid & 63;
  int nsent = 0;
  for (int b = 0; b < B_; b++) {
    int cnt = 0;
#pragma unroll
    for (int dd = 0; dd < D_; dd++) cnt += (ds[dd * 2] <= b) ? 1 : 0;
    nsent += ((cnt - 1) == d) ? 1 : 0;
  }
  float inv_node = 1.0f / fmaxf((float)nsent * (float)S_, 1.0f);
  float inv_doc  = 1.0f / fmaxf((float)(ds[d * 2 + 1] - ds[d * 2]), 1.0f);
  float acc = 0.f;
  for (int h = lane; h < H_; h += 64)
    acc += fabsf(qfp[d * H_ + h] * inv_doc - avgp[d * H_ + h] * inv_node);
  for (int off = 32; off; off >>= 1) acc += __shfl_xor(acc, off);
  if (lane == 0) out[d] = acc;
}

extern "C" void kernel_launch(void* const* d_in, const int* in_sizes, int n_in,
                              void* d_out, int out_size, void* d_ws, size_t ws_size,
                              hipStream_t stream) {
  const float* features     = (const float*)d_in[0];
  const int*   token_spans  = (const int*)d_in[1];
  const int*   masks        = (const int*)d_in[2];
  const int*   selidx       = (const int*)d_in[3];
  const int*   src          = (const int*)d_in[4];
  const int*   dst          = (const int*)d_in[5];
  const int*   doc_spans    = (const int*)d_in[6];
  const int*   segment_ids  = (const int*)d_in[7];
  const int*   is_head      = (const int*)d_in[8];
  const float* Wl[3]  = {(const float*)d_in[9],  (const float*)d_in[12], (const float*)d_in[15]};
  const float* alv[3] = {(const float*)d_in[10], (const float*)d_in[13], (const float*)d_in[16]};
  const float* arv[3] = {(const float*)d_in[11], (const float*)d_in[14], (const float*)d_in[17]};
  float* out = (float*)d_out;

  char* ws = (char*)d_ws;
  size_t off = 0;
  auto alloc = [&](size_t bytes) -> void* {
    void* p = ws + off;
    off = (off + bytes + 255) & ~(size_t)255;
    return p;
  };
  __hip_bfloat16* hA = (__hip_bfloat16*)alloc((size_t)N_ * H_ * 2);   // bf16 h
  __hip_bfloat16* hB = (__hip_bfloat16*)alloc((size_t)N_ * H_ * 2);   // bf16 z
  __hip_bfloat16* Wt = (__hip_bfloat16*)alloc((size_t)3 * H_ * H_ * 2);
  // ---- contiguous zero-fill region: avgp|qfp | el[3] | er[3] | counts ----
  float* avgp   = (float*)alloc((size_t)2 * D_ * H_ * 4);  // avgp | qfp
  float* qfp    = avgp + (size_t)D_ * H_;
  float* el     = (float*)alloc((size_t)3 * N_ * 4);
  float* er     = (float*)alloc((size_t)3 * N_ * 4);
  int*   counts = (int*)alloc((size_t)N_ * 4);
  size_t zero_bytes = (size_t)(2 * D_ * H_ + 6 * N_ + N_) * 4;
  // ---- rest of scratch ----
  int*   offs   = (int*)alloc((size_t)(N_ + 1) * 4);
  int*   cursor = (int*)alloc((size_t)N_ * 4);
  int*   esrc   = (int*)alloc((size_t)NE_ * 4);

  // one zero fill for all accumulators + counts
  hipMemsetAsync(avgp, 0, zero_bytes, stream);

  // CSR build (edges constant across layers)
  k_count<<<(NE_ + 255) / 256, 256, 0, stream>>>(dst, counts, NE_);
  k_scan<<<1, 1024, 0, stream>>>(counts, offs, cursor);
  k_scatter<<<(NE_ + 255) / 256, 256, 0, stream>>>(dst, src, cursor, esrc, NE_);

  // W transpose + bf16 convert (all 3 layers)
  k_wt<<<dim3(H_ / 32, H_ / 32, 3), 256, 0, stream>>>(Wl[0], Wl[1], Wl[2], Wt);

  // h0 = pooled selected token reps (bf16)
  k_token<<<N_, 192, 0, stream>>>(features, token_spans, masks, selidx, hA);

  // 3 GAT layers: hA(bf16) -> z(hB,bf16)+el/er -> hA(bf16)
  for (int i = 0; i < 3; i++) {
    k_gemm_bf16<<<dim3(N_ / 128, H_ / 128), 256, 0, stream>>>(
        hA, Wt + (size_t)i * H_ * H_, hB, alv[i], arv[i],
        el + (size_t)i * N_, er + (size_t)i * N_, N_, H_, H_);
    k_agg<<<N_ / 4, 256, 0, stream>>>(hB, el + (size_t)i * N_, er + (size_t)i * N_,
                                      offs, esrc, hA);
  }

  // doc-level reductions
  k_avg<<<dim3(B_, 8), 192, 0, stream>>>(hA, doc_spans, avgp);
  k_qf<<<dim3(B_, 32), 192, 0, stream>>>(features, masks, segment_ids, is_head, doc_spans, qfp);
  k_final<<<1, 512, 0, stream>>>(qfp, avgp, doc_spans, out);
}

// Round 6
// 261.463 us; speedup vs baseline: 2.7457x; 1.0166x over previous
//
#include <hip/hip_runtime.h>
#include <hip/hip_bf16.h>

// Problem constants (fixed by setup_inputs)
constexpr int B_ = 64, L_ = 512, H_ = 768, T_ = 256, S_ = 128, D_ = 8;
constexpr int N_ = B_ * S_;        // 8192 nodes
constexpr int E0_ = 16 * N_;       // 131072 random edges
constexpr int NE_ = E0_ + N_;      // + self loops = 139264
constexpr float NEG_SLOPE = 0.2f;
constexpr int KDIM = 768;          // GEMM K (= H_)

typedef __attribute__((ext_vector_type(8))) short short8v;
typedef __attribute__((ext_vector_type(4))) float f32x4;

#define GLOAD_LDS16(g, l) __builtin_amdgcn_global_load_lds( \
    (const __attribute__((address_space(1))) void*)(g), \
    (__attribute__((address_space(3))) void*)(l), 16, 0, 0)

__device__ __forceinline__ float bf2f(short s) {
  unsigned u = ((unsigned)(unsigned short)s) << 16;
  return __builtin_bit_cast(float, u);
}
__device__ __forceinline__ short f2bf(float f) {
  return (short)__bfloat16_as_ushort(__float2bfloat16(f));
}
__device__ __forceinline__ int docof(int b, const int* __restrict__ doc_spans) {
  int cnt = 0;
  for (int dd = 0; dd < D_; dd++) cnt += (doc_spans[dd * 2] <= b) ? 1 : 0;
  return cnt - 1;
}

// ------- fused: token span pooling (blocks 0..N-1) + W transpose (rest) ----
__global__ __launch_bounds__(256) void k_token_wt(const float* __restrict__ features,
                                                  const int* __restrict__ token_spans,
                                                  const int* __restrict__ masks,
                                                  const int* __restrict__ selidx,
                                                  __hip_bfloat16* __restrict__ h0,
                                                  const float* __restrict__ W0,
                                                  const float* __restrict__ W1,
                                                  const float* __restrict__ W2,
                                                  __hip_bfloat16* __restrict__ Wt) {
  int bid = blockIdx.x;
  if (bid < N_) {
    // ---- token pooling: one block per node, 192 active lanes ----
    if (threadIdx.x >= 192) return;
    int n = bid;
    int b = n / S_;
    int t = selidx[n];
    int st = token_spans[(b * T_ + t) * 2 + 0];
    int en = token_spans[(b * T_ + t) * 2 + 1];
    int tid = threadIdx.x;
    float4 a = make_float4(0.f, 0.f, 0.f, 0.f);
    int cnt = 0;
    for (int l = st; l < en; l++) {
      if (masks[b * L_ + l] > 0) {
        cnt++;
        float4 v = ((const float4*)(features + ((size_t)b * L_ + l) * H_))[tid];
        a.x += v.x; a.y += v.y; a.z += v.z; a.w += v.w;
      }
    }
    float sc = (en > 0) ? (1.0f / (float)max(cnt, 1)) : 0.0f;
    short4 o;
    o.x = f2bf(a.x * sc); o.y = f2bf(a.y * sc); o.z = f2bf(a.z * sc); o.w = f2bf(a.w * sc);
    ((short4*)(h0 + (size_t)n * H_))[tid] = o;
    return;
  }
  // ---- W transpose + bf16: Wt[layer][n][k] = W[layer][k][n] ----
  int wb = bid - N_;                     // 0..1727
  int layer = wb / 576;
  int rem = wb % 576;
  int k0 = (rem % 24) * 32, n0 = (rem / 24) * 32;
  const float* Ws[3] = {W0, W1, W2};
  const float* W = Ws[layer];
  __hip_bfloat16* O = Wt + (size_t)layer * H_ * H_;
  __shared__ float tbuf[32][33];
  int x = threadIdx.x % 32, y = threadIdx.x / 32;   // 32x8
  for (int i = 0; i < 32; i += 8)
    tbuf[y + i][x] = W[(size_t)(k0 + y + i) * H_ + n0 + x];
  __syncthreads();
  for (int i = 0; i < 32; i += 8)
    O[(size_t)(n0 + y + i) * H_ + k0 + x] = __float2bfloat16(tbuf[x][y + i]);
}

// ---------------- CSR build (edges constant across layers) ----------------
__global__ void k_count(const int* __restrict__ dst, int* __restrict__ counts, int ne) {
  int i = blockIdx.x * 256 + threadIdx.x;
  if (i < ne) atomicAdd(&counts[dst[i]], 1);
}

__global__ __launch_bounds__(1024) void k_scan(const int* __restrict__ counts,
                                               int* __restrict__ offs,
                                               int* __restrict__ cursor) {
  __shared__ int part[1024];
  int tid = threadIdx.x;
  int base = tid * 8;
  int loc[8];
  int s = 0;
  for (int i = 0; i < 8; i++) { loc[i] = s; s += counts[base + i]; }
  part[tid] = s;
  __syncthreads();
  for (int off = 1; off < 1024; off <<= 1) {
    int v = (tid >= off) ? part[tid - off] : 0;
    __syncthreads();
    part[tid] += v;
    __syncthreads();
  }
  int excl = (tid == 0) ? 0 : part[tid - 1];
  for (int i = 0; i < 8; i++) {
    int o = excl + loc[i];
    offs[base + i] = o;
    cursor[base + i] = o;
  }
  if (tid == 1023) offs[N_] = part[1023];
}

// scatter: store SOURCE NODE ID (not edge id) sorted by dst
__global__ void k_scatter(const int* __restrict__ dst, const int* __restrict__ src,
                          int* __restrict__ cursor, int* __restrict__ esrc, int ne) {
  int i = blockIdx.x * 256 + threadIdx.x;
  if (i < ne) { int p = atomicAdd(&cursor[dst[i]], 1); esrc[p] = src[i]; }
}

// ------ bf16 MFMA GEMM + fused el/er, 2-phase double-buffered LDS ---------
// 128x128 tile, BK=32, 4 waves; next tile's global_load_lds issued BEFORE
// the current tile's ds_read+MFMA so HBM latency hides under compute.
__global__ __launch_bounds__(256) void k_gemm_bf16(const __hip_bfloat16* __restrict__ A,
                                                   const __hip_bfloat16* __restrict__ Bt,
                                                   __hip_bfloat16* __restrict__ C,
                                                   const float* __restrict__ al,
                                                   const float* __restrict__ ar,
                                                   float* __restrict__ el,
                                                   float* __restrict__ er) {
  __shared__ __hip_bfloat16 As[2][128 * 32];
  __shared__ __hip_bfloat16 Bs[2][128 * 32];
  int tid = threadIdx.x;
  int bm = blockIdx.x * 128;
  int bn = blockIdx.y * 128;
  int w = tid >> 6;
  int l = tid & 63;
  int wr = w >> 1, wc = w & 1;
  int lr = l & 15;
  int lk = (l >> 4) * 8;
  f32x4 acc[4][4] = {};

  // per-thread staging coordinates (idx = i*256+tid; row=idx>>2, ck=(idx&3)*8)
  const __hip_bfloat16* gA[2];
  const __hip_bfloat16* gB[2];
  int ldsoff[2];
#pragma unroll
  for (int i = 0; i < 2; i++) {
    int idx = i * 256 + tid;
    int row = idx >> 2;
    int ck = (idx & 3) * 8;
    gA[i] = A + (size_t)(bm + row) * KDIM + ck;
    gB[i] = Bt + (size_t)(bn + row) * KDIM + ck;
    ldsoff[i] = idx * 8;
  }

  auto stage = [&](int buf, int k0) {
#pragma unroll
    for (int i = 0; i < 2; i++) GLOAD_LDS16(gA[i] + k0, &As[buf][ldsoff[i]]);
#pragma unroll
    for (int i = 0; i < 2; i++) GLOAD_LDS16(gB[i] + k0, &Bs[buf][ldsoff[i]]);
  };

  stage(0, 0);
  __syncthreads();                       // compiler drains vmcnt before barrier

  constexpr int NT = KDIM / 32;          // 24 K-steps
  for (int t = 0; t < NT; t++) {
    int cur = t & 1;
    if (t < NT - 1) stage(cur ^ 1, (t + 1) * 32);   // prefetch flies under MFMA
    short8v a_frag[4], b_frag[4];
#pragma unroll
    for (int m = 0; m < 4; m++)
      a_frag[m] = *(const short8v*)&As[cur][(wr * 64 + m * 16 + lr) * 32 + lk];
#pragma unroll
    for (int n = 0; n < 4; n++)
      b_frag[n] = *(const short8v*)&Bs[cur][(wc * 64 + n * 16 + lr) * 32 + lk];
#pragma unroll
    for (int m = 0; m < 4; m++)
#pragma unroll
      for (int n = 0; n < 4; n++)
        acc[m][n] = __builtin_amdgcn_mfma_f32_16x16x32_bf16(a_frag[m], b_frag[n], acc[m][n], 0, 0, 0);
    __syncthreads();
  }

  // per-lane al/ar for this block's columns: col = bn + wc*64 + n*16 + lr
  float alv[4], arv[4];
#pragma unroll
  for (int n = 0; n < 4; n++) {
    int col = bn + wc * 64 + n * 16 + lr;
    alv[n] = al[col]; arv[n] = ar[col];
  }
  // C/D layout: col = lane&15, row = (lane>>4)*4 + r  [verified m89/m91]
#pragma unroll
  for (int m = 0; m < 4; m++) {
    int rbase = bm + wr * 64 + m * 16 + (l >> 4) * 4;
#pragma unroll
    for (int n = 0; n < 4; n++) {
      int col = bn + wc * 64 + n * 16 + lr;
#pragma unroll
      for (int r = 0; r < 4; r++)
        C[(size_t)(rbase + r) * H_ + col] = __float2bfloat16(acc[m][n][r]);
    }
    // fused el/er partials: reduce over the 16 lanes of each row group
#pragma unroll
    for (int r = 0; r < 4; r++) {
      float pel = 0.f, per_ = 0.f;
#pragma unroll
      for (int n = 0; n < 4; n++) {
        pel  += acc[m][n][r] * alv[n];
        per_ += acc[m][n][r] * arv[n];
      }
#pragma unroll
      for (int off2 = 1; off2 < 16; off2 <<= 1) {
        pel  += __shfl_xor(pel,  off2);
        per_ += __shfl_xor(per_, off2);
      }
      if (lr == 0) {
        atomicAdd(&el[rbase + r], pel);
        atomicAdd(&er[rbase + r], per_);
      }
    }
  }
}

// ---------------- wave-per-dst-node softmax + weighted agg + elu ----------
__global__ __launch_bounds__(256) void k_agg(const __hip_bfloat16* __restrict__ z,
                                             const float* __restrict__ el,
                                             const float* __restrict__ er,
                                             const int* __restrict__ offs,
                                             const int* __restrict__ esrc,
                                             __hip_bfloat16* __restrict__ hout) {
  int wv = threadIdx.x >> 6, lane = threadIdx.x & 63;
  int n = blockIdx.x * 4 + wv;
  int o0 = offs[n];
  int deg = offs[n + 1] - o0;
  float ern = er[n];
  float acc[12] = {};

  if (deg <= 64) {
    float w_ = 0.f; int s_ = 0;
    if (lane < deg) {
      s_ = esrc[o0 + lane];
      float v = el[s_] + ern;
      w_ = v > 0.f ? v : NEG_SLOPE * v;
    } else {
      w_ = -1e30f;
    }
    float m = w_;
    for (int off = 32; off; off >>= 1) m = fmaxf(m, __shfl_xor(m, off));
    float ex = (lane < deg) ? __expf(w_ - m) : 0.f;
    float sum = ex;
    for (int off = 32; off; off >>= 1) sum += __shfl_xor(sum, off);
    w_ = ex / sum;
    for (int j = 0; j < deg; j++) {
      float wj = __shfl(w_, j);
      int sj = __shfl(s_, j);
      const short4* zr = (const short4*)(z + (size_t)sj * H_);
#pragma unroll
      for (int i = 0; i < 3; i++) {
        short4 v = zr[lane + i * 64];
        acc[i * 4 + 0] += wj * bf2f(v.x);
        acc[i * 4 + 1] += wj * bf2f(v.y);
        acc[i * 4 + 2] += wj * bf2f(v.z);
        acc[i * 4 + 3] += wj * bf2f(v.w);
      }
    }
  } else {
    float lmax = -1e30f;
    for (int i = lane; i < deg; i += 64) {
      float v = el[esrc[o0 + i]] + ern;
      v = v > 0.f ? v : NEG_SLOPE * v;
      lmax = fmaxf(lmax, v);
    }
    for (int off = 32; off; off >>= 1) lmax = fmaxf(lmax, __shfl_xor(lmax, off));
    float lsum = 0.f;
    for (int i = lane; i < deg; i += 64) {
      float v = el[esrc[o0 + i]] + ern;
      v = v > 0.f ? v : NEG_SLOPE * v;
      lsum += __expf(v - lmax);
    }
    for (int off = 32; off; off >>= 1) lsum += __shfl_xor(lsum, off);
    float inv = 1.0f / lsum;
    for (int base = 0; base < deg; base += 64) {
      int chunk = min(64, deg - base);
      float w_ = 0.f; int s_ = 0;
      if (lane < chunk) {
        s_ = esrc[o0 + base + lane];
        float v = el[s_] + ern;
        v = v > 0.f ? v : NEG_SLOPE * v;
        w_ = __expf(v - lmax) * inv;
      }
      for (int j = 0; j < chunk; j++) {
        float wj = __shfl(w_, j);
        int sj = __shfl(s_, j);
        const short4* zr = (const short4*)(z + (size_t)sj * H_);
#pragma unroll
        for (int i = 0; i < 3; i++) {
          short4 v = zr[lane + i * 64];
          acc[i * 4 + 0] += wj * bf2f(v.x);
          acc[i * 4 + 1] += wj * bf2f(v.y);
          acc[i * 4 + 2] += wj * bf2f(v.z);
          acc[i * 4 + 3] += wj * bf2f(v.w);
        }
      }
    }
  }

  short4* ho = (short4*)(hout + (size_t)n * H_);
#pragma unroll
  for (int i = 0; i < 3; i++) {
    float e0 = acc[i * 4 + 0]; e0 = e0 > 0.f ? e0 : __expf(e0) - 1.f;
    float e1 = acc[i * 4 + 1]; e1 = e1 > 0.f ? e1 : __expf(e1) - 1.f;
    float e2 = acc[i * 4 + 2]; e2 = e2 > 0.f ? e2 : __expf(e2) - 1.f;
    float e3 = acc[i * 4 + 3]; e3 = e3 > 0.f ? e3 : __expf(e3) - 1.f;
    short4 o; o.x = f2bf(e0); o.y = f2bf(e1); o.z = f2bf(e2); o.w = f2bf(e3);
    ho[lane + i * 64] = o;
  }
}

// ------- fused doc reductions: grid (B, 40): y<8 -> avg, y>=8 -> qf -------
__global__ __launch_bounds__(192) void k_avgqf(const __hip_bfloat16* __restrict__ h,
                                               const float* __restrict__ features,
                                               const int* __restrict__ masks,
                                               const int* __restrict__ segment_ids,
                                               const int* __restrict__ is_head,
                                               const int* __restrict__ doc_spans,
                                               float* __restrict__ avgp,
                                               float* __restrict__ qfp) {
  int b = blockIdx.x;
  int y = blockIdx.y;
  int tid = threadIdx.x;
  int d = docof(b, doc_spans);
  if (y < 8) {
    int s0 = y * 16;
    float4 a = make_float4(0.f, 0.f, 0.f, 0.f);
    for (int i = 0; i < 16; i++) {
      short4 v = ((const short4*)(h + ((size_t)(b * S_ + s0 + i)) * H_))[tid];
      a.x += bf2f(v.x); a.y += bf2f(v.y); a.z += bf2f(v.z); a.w += bf2f(v.w);
    }
    atomicAdd(&avgp[d * H_ + tid * 4 + 0], a.x);
    atomicAdd(&avgp[d * H_ + tid * 4 + 1], a.y);
    atomicAdd(&avgp[d * H_ + tid * 4 + 2], a.z);
    atomicAdd(&avgp[d * H_ + tid * 4 + 3], a.w);
  } else {
    int l0 = (y - 8) * 16;
    __shared__ float qm[16];
    if (tid < 16) {
      int l = l0 + tid;
      qm[tid] = (is_head[b * L_ + l] != 2 && segment_ids[b * L_ + l] == 0 && masks[b * L_ + l] > 0) ? 1.0f : 0.0f;
    }
    __syncthreads();
    float4 a = make_float4(0.f, 0.f, 0.f, 0.f);
    for (int i = 0; i < 16; i++) {
      if (qm[i] != 0.f) {
        float4 v = ((const float4*)(features + ((size_t)b * L_ + l0 + i) * H_))[tid];
        a.x += v.x; a.y += v.y; a.z += v.z; a.w += v.w;
      }
    }
    atomicAdd(&qfp[d * H_ + tid * 4 + 0], a.x);
    atomicAdd(&qfp[d * H_ + tid * 4 + 1], a.y);
    atomicAdd(&qfp[d * H_ + tid * 4 + 2], a.z);
    atomicAdd(&qfp[d * H_ + tid * 4 + 3], a.w);
  }
}

// ---------------- final: out[d] = sum_h |qf/doccnt - avg/nodecnt| ----------
__global__ __launch_bounds__(512) void k_final(const float* __restrict__ qfp,
                                               const float* __restrict__ avgp,
                                               const int* __restrict__ doc_spans,
                                               float* __restrict__ out) {
  __shared__ int ds[D_ * 2];
  int tid = threadIdx.x;
  if (tid < D_ * 2) ds[tid] = doc_spans[tid];
  __syncthreads();
  int d = tid >> 6, lane = tid & 63;
  int nsent = 0;
  for (int b = 0; b < B_; b++) {
    int cnt = 0;
#pragma unroll
    for (int dd = 0; dd < D_; dd++) cnt += (ds[dd * 2] <= b) ? 1 : 0;
    nsent += ((cnt - 1) == d) ? 1 : 0;
  }
  float inv_node = 1.0f / fmaxf((float)nsent * (float)S_, 1.0f);
  float inv_doc  = 1.0f / fmaxf((float)(ds[d * 2 + 1] - ds[d * 2]), 1.0f);
  float acc = 0.f;
  for (int h = lane; h < H_; h += 64)
    acc += fabsf(qfp[d * H_ + h] * inv_doc - avgp[d * H_ + h] * inv_node);
  for (int off = 32; off; off >>= 1) acc += __shfl_xor(acc, off);
  if (lane == 0) out[d] = acc;
}

extern "C" void kernel_launch(void* const* d_in, const int* in_sizes, int n_in,
                              void* d_out, int out_size, void* d_ws, size_t ws_size,
                              hipStream_t stream) {
  const float* features     = (const float*)d_in[0];
  const int*   token_spans  = (const int*)d_in[1];
  const int*   masks        = (const int*)d_in[2];
  const int*   selidx       = (const int*)d_in[3];
  const int*   src          = (const int*)d_in[4];
  const int*   dst          = (const int*)d_in[5];
  const int*   doc_spans    = (const int*)d_in[6];
  const int*   segment_ids  = (const int*)d_in[7];
  const int*   is_head      = (const int*)d_in[8];
  const float* Wl[3]  = {(const float*)d_in[9],  (const float*)d_in[12], (const float*)d_in[15]};
  const float* alv[3] = {(const float*)d_in[10], (const float*)d_in[13], (const float*)d_in[16]};
  const float* arv[3] = {(const float*)d_in[11], (const float*)d_in[14], (const float*)d_in[17]};
  float* out = (float*)d_out;

  char* ws = (char*)d_ws;
  size_t off = 0;
  auto alloc = [&](size_t bytes) -> void* {
    void* p = ws + off;
    off = (off + bytes + 255) & ~(size_t)255;
    return p;
  };
  __hip_bfloat16* hA = (__hip_bfloat16*)alloc((size_t)N_ * H_ * 2);   // bf16 h
  __hip_bfloat16* hB = (__hip_bfloat16*)alloc((size_t)N_ * H_ * 2);   // bf16 z
  __hip_bfloat16* Wt = (__hip_bfloat16*)alloc((size_t)3 * H_ * H_ * 2);
  // ---- contiguous zero-fill region: avgp|qfp | el[3] | er[3] | counts ----
  float* avgp   = (float*)alloc((size_t)2 * D_ * H_ * 4);  // avgp | qfp
  float* qfp    = avgp + (size_t)D_ * H_;
  float* el     = (float*)alloc((size_t)3 * N_ * 4);
  float* er     = (float*)alloc((size_t)3 * N_ * 4);
  int*   counts = (int*)alloc((size_t)N_ * 4);
  size_t zero_bytes = (size_t)(2 * D_ * H_ + 6 * N_ + N_) * 4;
  // ---- rest of scratch ----
  int*   offs   = (int*)alloc((size_t)(N_ + 1) * 4);
  int*   cursor = (int*)alloc((size_t)N_ * 4);
  int*   esrc   = (int*)alloc((size_t)NE_ * 4);

  // one zero fill for all accumulators + counts
  hipMemsetAsync(avgp, 0, zero_bytes, stream);

  // CSR build (edges constant across layers)
  k_count<<<(NE_ + 255) / 256, 256, 0, stream>>>(dst, counts, NE_);
  k_scan<<<1, 1024, 0, stream>>>(counts, offs, cursor);
  k_scatter<<<(NE_ + 255) / 256, 256, 0, stream>>>(dst, src, cursor, esrc, NE_);

  // token pooling + W transposes in one dispatch
  k_token_wt<<<N_ + 3 * 576, 256, 0, stream>>>(features, token_spans, masks, selidx,
                                               hA, Wl[0], Wl[1], Wl[2], Wt);

  // 3 GAT layers: hA(bf16) -> z(hB,bf16)+el/er -> hA(bf16)
  for (int i = 0; i < 3; i++) {
    k_gemm_bf16<<<dim3(N_ / 128, H_ / 128), 256, 0, stream>>>(
        hA, Wt + (size_t)i * H_ * H_, hB, alv[i], arv[i],
        el + (size_t)i * N_, er + (size_t)i * N_);
    k_agg<<<N_ / 4, 256, 0, stream>>>(hB, el + (size_t)i * N_, er + (size_t)i * N_,
                                      offs, esrc, hA);
  }

  // doc-level reductions (avg + qf fused)
  k_avgqf<<<dim3(B_, 40), 192, 0, stream>>>(hA, features, masks, segment_ids, is_head,
                                            doc_spans, avgp, qfp);
  k_final<<<1, 512, 0, stream>>>(qfp, avgp, doc_spans, out);
}

// Round 7
// 210.686 us; speedup vs baseline: 3.4074x; 1.2410x over previous
//
#include <hip/hip_runtime.h>
#include <hip/hip_bf16.h>

// Problem constants (fixed by setup_inputs)
constexpr int B_ = 64, L_ = 512, H_ = 768, T_ = 256, S_ = 128, D_ = 8;
constexpr int N_ = B_ * S_;        // 8192 nodes
constexpr int E0_ = 16 * N_;       // 131072 random edges
constexpr int NE_ = E0_ + N_;      // + self loops = 139264
constexpr float NEG_SLOPE = 0.2f;
constexpr int KDIM = 768;          // GEMM K (= H_)
constexpr int NB_WT = 3 * 576;     // W-transpose blocks
constexpr int NB_ZERO = 68;        // zero-fill blocks (68*256 int4 = 272 KB)

typedef __attribute__((ext_vector_type(8))) short short8v;
typedef __attribute__((ext_vector_type(4))) float f32x4;

#define GLOAD_LDS16(g, l) __builtin_amdgcn_global_load_lds( \
    (const __attribute__((address_space(1))) void*)(g), \
    (__attribute__((address_space(3))) void*)(l), 16, 0, 0)

__device__ __forceinline__ float bf2f(short s) {
  unsigned u = ((unsigned)(unsigned short)s) << 16;
  return __builtin_bit_cast(float, u);
}
__device__ __forceinline__ short f2bf(float f) {
  return (short)__bfloat16_as_ushort(__float2bfloat16(f));
}
__device__ __forceinline__ int docof(int b, const int* __restrict__ doc_spans) {
  int cnt = 0;
  for (int dd = 0; dd < D_; dd++) cnt += (doc_spans[dd * 2] <= b) ? 1 : 0;
  return cnt - 1;
}

// -- fused: token pooling [0,N) + W transpose [N,N+1728) + zero-fill (rest) --
__global__ __launch_bounds__(256) void k_token_wt(const float* __restrict__ features,
                                                  const int* __restrict__ token_spans,
                                                  const int* __restrict__ masks,
                                                  const int* __restrict__ selidx,
                                                  __hip_bfloat16* __restrict__ h0,
                                                  const float* __restrict__ W0,
                                                  const float* __restrict__ W1,
                                                  const float* __restrict__ W2,
                                                  __hip_bfloat16* __restrict__ Wt,
                                                  int4* __restrict__ zero_base) {
  int bid = blockIdx.x;
  if (bid < N_) {
    // ---- token pooling: one block per node, 192 active lanes ----
    if (threadIdx.x >= 192) return;
    int n = bid;
    int b = n / S_;
    int t = selidx[n];
    int st = token_spans[(b * T_ + t) * 2 + 0];
    int en = token_spans[(b * T_ + t) * 2 + 1];
    int tid = threadIdx.x;
    float4 a = make_float4(0.f, 0.f, 0.f, 0.f);
    int cnt = 0;
    for (int l = st; l < en; l++) {
      if (masks[b * L_ + l] > 0) {
        cnt++;
        float4 v = ((const float4*)(features + ((size_t)b * L_ + l) * H_))[tid];
        a.x += v.x; a.y += v.y; a.z += v.z; a.w += v.w;
      }
    }
    float sc = (en > 0) ? (1.0f / (float)max(cnt, 1)) : 0.0f;
    short4 o;
    o.x = f2bf(a.x * sc); o.y = f2bf(a.y * sc); o.z = f2bf(a.z * sc); o.w = f2bf(a.w * sc);
    ((short4*)(h0 + (size_t)n * H_))[tid] = o;
    return;
  }
  if (bid < N_ + NB_WT) {
    // ---- W transpose + bf16: Wt[layer][n][k] = W[layer][k][n] ----
    int wb = bid - N_;                     // 0..1727
    int layer = wb / 576;
    int rem = wb % 576;
    int k0 = (rem % 24) * 32, n0 = (rem / 24) * 32;
    const float* Ws[3] = {W0, W1, W2};
    const float* W = Ws[layer];
    __hip_bfloat16* O = Wt + (size_t)layer * H_ * H_;
    __shared__ float tbuf[32][33];
    int x = threadIdx.x % 32, y = threadIdx.x / 32;   // 32x8
    for (int i = 0; i < 32; i += 8)
      tbuf[y + i][x] = W[(size_t)(k0 + y + i) * H_ + n0 + x];
    __syncthreads();
    for (int i = 0; i < 32; i += 8)
      O[(size_t)(n0 + y + i) * H_ + k0 + x] = __float2bfloat16(tbuf[x][y + i]);
    return;
  }
  // ---- zero accumulators (avgp|qfp|el|er|counts contiguous, 272 KB) ----
  int zi = bid - N_ - NB_WT;
  zero_base[zi * 256 + threadIdx.x] = make_int4(0, 0, 0, 0);
}

// ---------------- CSR build (edges constant across layers) ----------------
__global__ void k_count(const int* __restrict__ dst, int* __restrict__ counts, int ne) {
  int i = blockIdx.x * 256 + threadIdx.x;
  if (i < ne) atomicAdd(&counts[dst[i]], 1);
}

__global__ __launch_bounds__(1024) void k_scan(const int* __restrict__ counts,
                                               int* __restrict__ offs,
                                               int* __restrict__ cursor) {
  __shared__ int part[1024];
  int tid = threadIdx.x;
  int base = tid * 8;
  int loc[8];
  int s = 0;
  for (int i = 0; i < 8; i++) { loc[i] = s; s += counts[base + i]; }
  part[tid] = s;
  __syncthreads();
  for (int off = 1; off < 1024; off <<= 1) {
    int v = (tid >= off) ? part[tid - off] : 0;
    __syncthreads();
    part[tid] += v;
    __syncthreads();
  }
  int excl = (tid == 0) ? 0 : part[tid - 1];
  for (int i = 0; i < 8; i++) {
    int o = excl + loc[i];
    offs[base + i] = o;
    cursor[base + i] = o;
  }
  if (tid == 1023) offs[N_] = part[1023];
}

// scatter: store SOURCE NODE ID (not edge id) sorted by dst
__global__ void k_scatter(const int* __restrict__ dst, const int* __restrict__ src,
                          int* __restrict__ cursor, int* __restrict__ esrc, int ne) {
  int i = blockIdx.x * 256 + threadIdx.x;
  if (i < ne) { int p = atomicAdd(&cursor[dst[i]], 1); esrc[p] = src[i]; }
}

// ------ bf16 MFMA GEMM + fused el/er; z written as fp8 e4m3 ---------------
// 128x128 tile, BK=32, 4 waves, double-buffered LDS.
__global__ __launch_bounds__(256) void k_gemm_bf16(const __hip_bfloat16* __restrict__ A,
                                                   const __hip_bfloat16* __restrict__ Bt,
                                                   unsigned char* __restrict__ C,
                                                   const float* __restrict__ al,
                                                   const float* __restrict__ ar,
                                                   float* __restrict__ el,
                                                   float* __restrict__ er) {
  __shared__ __hip_bfloat16 As[2][128 * 32];
  __shared__ __hip_bfloat16 Bs[2][128 * 32];
  int tid = threadIdx.x;
  int bm = blockIdx.x * 128;
  int bn = blockIdx.y * 128;
  int w = tid >> 6;
  int l = tid & 63;
  int wr = w >> 1, wc = w & 1;
  int lr = l & 15;
  int lk = (l >> 4) * 8;
  f32x4 acc[4][4] = {};

  const __hip_bfloat16* gA[2];
  const __hip_bfloat16* gB[2];
  int ldsoff[2];
#pragma unroll
  for (int i = 0; i < 2; i++) {
    int idx = i * 256 + tid;
    int row = idx >> 2;
    int ck = (idx & 3) * 8;
    gA[i] = A + (size_t)(bm + row) * KDIM + ck;
    gB[i] = Bt + (size_t)(bn + row) * KDIM + ck;
    ldsoff[i] = idx * 8;
  }

  auto stage = [&](int buf, int k0) {
#pragma unroll
    for (int i = 0; i < 2; i++) GLOAD_LDS16(gA[i] + k0, &As[buf][ldsoff[i]]);
#pragma unroll
    for (int i = 0; i < 2; i++) GLOAD_LDS16(gB[i] + k0, &Bs[buf][ldsoff[i]]);
  };

  stage(0, 0);
  __syncthreads();

  constexpr int NT = KDIM / 32;          // 24 K-steps
  for (int t = 0; t < NT; t++) {
    int cur = t & 1;
    if (t < NT - 1) stage(cur ^ 1, (t + 1) * 32);
    short8v a_frag[4], b_frag[4];
#pragma unroll
    for (int m = 0; m < 4; m++)
      a_frag[m] = *(const short8v*)&As[cur][(wr * 64 + m * 16 + lr) * 32 + lk];
#pragma unroll
    for (int n = 0; n < 4; n++)
      b_frag[n] = *(const short8v*)&Bs[cur][(wc * 64 + n * 16 + lr) * 32 + lk];
#pragma unroll
    for (int m = 0; m < 4; m++)
#pragma unroll
      for (int n = 0; n < 4; n++)
        acc[m][n] = __builtin_amdgcn_mfma_f32_16x16x32_bf16(a_frag[m], b_frag[n], acc[m][n], 0, 0, 0);
    __syncthreads();
  }

  // per-lane al/ar for this block's columns: col = bn + wc*64 + n*16 + lr
  float alv[4], arv[4];
#pragma unroll
  for (int n = 0; n < 4; n++) {
    int col = bn + wc * 64 + n * 16 + lr;
    alv[n] = al[col]; arv[n] = ar[col];
  }
  // C/D layout: col = lane&15, row = (lane>>4)*4 + r  [verified m89/m91]
#pragma unroll
  for (int m = 0; m < 4; m++) {
    int rbase = bm + wr * 64 + m * 16 + (l >> 4) * 4;
#pragma unroll
    for (int n = 0; n < 4; n++) {
      int col = bn + wc * 64 + n * 16 + lr;
#pragma unroll
      for (int r = 0; r < 4; r++) {
        float v = acc[m][n][r];
        int pk = __builtin_amdgcn_cvt_pk_fp8_f32(v, v, 0, false);
        C[(size_t)(rbase + r) * H_ + col] = (unsigned char)(pk & 0xff);
      }
    }
    // fused el/er partials: reduce over the 16 lanes of each row group
#pragma unroll
    for (int r = 0; r < 4; r++) {
      float pel = 0.f, per_ = 0.f;
#pragma unroll
      for (int n = 0; n < 4; n++) {
        pel  += acc[m][n][r] * alv[n];
        per_ += acc[m][n][r] * arv[n];
      }
#pragma unroll
      for (int off2 = 1; off2 < 16; off2 <<= 1) {
        pel  += __shfl_xor(pel,  off2);
        per_ += __shfl_xor(per_, off2);
      }
      if (lr == 0) {
        atomicAdd(&el[rbase + r], pel);
        atomicAdd(&er[rbase + r], per_);
      }
    }
  }
}

// ------- wave-per-dst-node softmax + weighted agg (fp8 z) + elu -----------
__global__ __launch_bounds__(256) void k_agg(const unsigned char* __restrict__ z,
                                             const float* __restrict__ el,
                                             const float* __restrict__ er,
                                             const int* __restrict__ offs,
                                             const int* __restrict__ esrc,
                                             __hip_bfloat16* __restrict__ hout) {
  int wv = threadIdx.x >> 6, lane = threadIdx.x & 63;
  int n = blockIdx.x * 4 + wv;
  int o0 = offs[n];
  int deg = offs[n + 1] - o0;
  float ern = er[n];
  float acc[12] = {};

  if (deg <= 64) {
    float w_ = 0.f; int s_ = 0;
    if (lane < deg) {
      s_ = esrc[o0 + lane];
      float v = el[s_] + ern;
      w_ = v > 0.f ? v : NEG_SLOPE * v;
    } else {
      w_ = -1e30f;
    }
    float m = w_;
    for (int off = 32; off; off >>= 1) m = fmaxf(m, __shfl_xor(m, off));
    float ex = (lane < deg) ? __expf(w_ - m) : 0.f;
    float sum = ex;
    for (int off = 32; off; off >>= 1) sum += __shfl_xor(sum, off);
    w_ = ex / sum;
    for (int j = 0; j < deg; j++) {
      float wj = __shfl(w_, j);
      int sj = __shfl(s_, j);
      const unsigned* zr = (const unsigned*)(z + (size_t)sj * H_);
#pragma unroll
      for (int i = 0; i < 3; i++) {
        unsigned u = zr[lane + i * 64];
        acc[i * 4 + 0] += wj * __builtin_amdgcn_cvt_f32_fp8(u, 0);
        acc[i * 4 + 1] += wj * __builtin_amdgcn_cvt_f32_fp8(u, 1);
        acc[i * 4 + 2] += wj * __builtin_amdgcn_cvt_f32_fp8(u, 2);
        acc[i * 4 + 3] += wj * __builtin_amdgcn_cvt_f32_fp8(u, 3);
      }
    }
  } else {
    float lmax = -1e30f;
    for (int i = lane; i < deg; i += 64) {
      float v = el[esrc[o0 + i]] + ern;
      v = v > 0.f ? v : NEG_SLOPE * v;
      lmax = fmaxf(lmax, v);
    }
    for (int off = 32; off; off >>= 1) lmax = fmaxf(lmax, __shfl_xor(lmax, off));
    float lsum = 0.f;
    for (int i = lane; i < deg; i += 64) {
      float v = el[esrc[o0 + i]] + ern;
      v = v > 0.f ? v : NEG_SLOPE * v;
      lsum += __expf(v - lmax);
    }
    for (int off = 32; off; off >>= 1) lsum += __shfl_xor(lsum, off);
    float inv = 1.0f / lsum;
    for (int base = 0; base < deg; base += 64) {
      int chunk = min(64, deg - base);
      float w_ = 0.f; int s_ = 0;
      if (lane < chunk) {
        s_ = esrc[o0 + base + lane];
        float v = el[s_] + ern;
        v = v > 0.f ? v : NEG_SLOPE * v;
        w_ = __expf(v - lmax) * inv;
      }
      for (int j = 0; j < chunk; j++) {
        float wj = __shfl(w_, j);
        int sj = __shfl(s_, j);
        const unsigned* zr = (const unsigned*)(z + (size_t)sj * H_);
#pragma unroll
        for (int i = 0; i < 3; i++) {
          unsigned u = zr[lane + i * 64];
          acc[i * 4 + 0] += wj * __builtin_amdgcn_cvt_f32_fp8(u, 0);
          acc[i * 4 + 1] += wj * __builtin_amdgcn_cvt_f32_fp8(u, 1);
          acc[i * 4 + 2] += wj * __builtin_amdgcn_cvt_f32_fp8(u, 2);
          acc[i * 4 + 3] += wj * __builtin_amdgcn_cvt_f32_fp8(u, 3);
        }
      }
    }
  }

  short4* ho = (short4*)(hout + (size_t)n * H_);
#pragma unroll
  for (int i = 0; i < 3; i++) {
    float e0 = acc[i * 4 + 0]; e0 = e0 > 0.f ? e0 : __expf(e0) - 1.f;
    float e1 = acc[i * 4 + 1]; e1 = e1 > 0.f ? e1 : __expf(e1) - 1.f;
    float e2 = acc[i * 4 + 2]; e2 = e2 > 0.f ? e2 : __expf(e2) - 1.f;
    float e3 = acc[i * 4 + 3]; e3 = e3 > 0.f ? e3 : __expf(e3) - 1.f;
    short4 o; o.x = f2bf(e0); o.y = f2bf(e1); o.z = f2bf(e2); o.w = f2bf(e3);
    ho[lane + i * 64] = o;
  }
}

// ------- fused doc reductions: grid (B, 16): y<8 -> avg, y>=8 -> qf -------
__global__ __launch_bounds__(192) void k_avgqf(const __hip_bfloat16* __restrict__ h,
                                               const float* __restrict__ features,
                                               const int* __restrict__ masks,
                                               const int* __restrict__ segment_ids,
                                               const int* __restrict__ is_head,
                                               const int* __restrict__ doc_spans,
                                               float* __restrict__ avgp,
                                               float* __restrict__ qfp) {
  int b = blockIdx.x;
  int y = blockIdx.y;
  int tid = threadIdx.x;
  int d = docof(b, doc_spans);
  if (y < 8) {
    int s0 = y * 16;
    float4 a = make_float4(0.f, 0.f, 0.f, 0.f);
    for (int i = 0; i < 16; i++) {
      short4 v = ((const short4*)(h + ((size_t)(b * S_ + s0 + i)) * H_))[tid];
      a.x += bf2f(v.x); a.y += bf2f(v.y); a.z += bf2f(v.z); a.w += bf2f(v.w);
    }
    atomicAdd(&avgp[d * H_ + tid * 4 + 0], a.x);
    atomicAdd(&avgp[d * H_ + tid * 4 + 1], a.y);
    atomicAdd(&avgp[d * H_ + tid * 4 + 2], a.z);
    atomicAdd(&avgp[d * H_ + tid * 4 + 3], a.w);
  } else {
    int l0 = (y - 8) * 64;
    __shared__ float qm[64];
    if (tid < 64) {
      int l = l0 + tid;
      qm[tid] = (is_head[b * L_ + l] != 2 && segment_ids[b * L_ + l] == 0 && masks[b * L_ + l] > 0) ? 1.0f : 0.0f;
    }
    __syncthreads();
    float4 a = make_float4(0.f, 0.f, 0.f, 0.f);
    for (int i = 0; i < 64; i++) {
      if (qm[i] != 0.f) {
        float4 v = ((const float4*)(features + ((size_t)b * L_ + l0 + i) * H_))[tid];
        a.x += v.x; a.y += v.y; a.z += v.z; a.w += v.w;
      }
    }
    atomicAdd(&qfp[d * H_ + tid * 4 + 0], a.x);
    atomicAdd(&qfp[d * H_ + tid * 4 + 1], a.y);
    atomicAdd(&qfp[d * H_ + tid * 4 + 2], a.z);
    atomicAdd(&qfp[d * H_ + tid * 4 + 3], a.w);
  }
}

// ---------------- final: out[d] = sum_h |qf/doccnt - avg/nodecnt| ----------
__global__ __launch_bounds__(512) void k_final(const float* __restrict__ qfp,
                                               const float* __restrict__ avgp,
                                               const int* __restrict__ doc_spans,
                                               float* __restrict__ out) {
  __shared__ int ds[D_ * 2];
  int tid = threadIdx.x;
  if (tid < D_ * 2) ds[tid] = doc_spans[tid];
  __syncthreads();
  int d = tid >> 6, lane = tid & 63;
  int nsent = 0;
  for (int b = 0; b < B_; b++) {
    int cnt = 0;
#pragma unroll
    for (int dd = 0; dd < D_; dd++) cnt += (ds[dd * 2] <= b) ? 1 : 0;
    nsent += ((cnt - 1) == d) ? 1 : 0;
  }
  float inv_node = 1.0f / fmaxf((float)nsent * (float)S_, 1.0f);
  float inv_doc  = 1.0f / fmaxf((float)(ds[d * 2 + 1] - ds[d * 2]), 1.0f);
  float acc = 0.f;
  for (int h = lane; h < H_; h += 64)
    acc += fabsf(qfp[d * H_ + h] * inv_doc - avgp[d * H_ + h] * inv_node);
  for (int off = 32; off; off >>= 1) acc += __shfl_xor(acc, off);
  if (lane == 0) out[d] = acc;
}

extern "C" void kernel_launch(void* const* d_in, const int* in_sizes, int n_in,
                              void* d_out, int out_size, void* d_ws, size_t ws_size,
                              hipStream_t stream) {
  const float* features     = (const float*)d_in[0];
  const int*   token_spans  = (const int*)d_in[1];
  const int*   masks        = (const int*)d_in[2];
  const int*   selidx       = (const int*)d_in[3];
  const int*   src          = (const int*)d_in[4];
  const int*   dst          = (const int*)d_in[5];
  const int*   doc_spans    = (const int*)d_in[6];
  const int*   segment_ids  = (const int*)d_in[7];
  const int*   is_head      = (const int*)d_in[8];
  const float* Wl[3]  = {(const float*)d_in[9],  (const float*)d_in[12], (const float*)d_in[15]};
  const float* alv[3] = {(const float*)d_in[10], (const float*)d_in[13], (const float*)d_in[16]};
  const float* arv[3] = {(const float*)d_in[11], (const float*)d_in[14], (const float*)d_in[17]};
  float* out = (float*)d_out;

  char* ws = (char*)d_ws;
  size_t off = 0;
  auto alloc = [&](size_t bytes) -> void* {
    void* p = ws + off;
    off = (off + bytes + 255) & ~(size_t)255;
    return p;
  };
  __hip_bfloat16* hA = (__hip_bfloat16*)alloc((size_t)N_ * H_ * 2);   // bf16 h
  unsigned char*  hB = (unsigned char*)alloc((size_t)N_ * H_);        // fp8 z
  __hip_bfloat16* Wt = (__hip_bfloat16*)alloc((size_t)3 * H_ * H_ * 2);
  // ---- contiguous zero-fill region: avgp|qfp | el[3] | er[3] | counts ----
  // sizes are all multiples of 256 B so the region is contiguous.
  float* avgp   = (float*)alloc((size_t)2 * D_ * H_ * 4);  // avgp | qfp
  float* qfp    = avgp + (size_t)D_ * H_;
  float* el     = (float*)alloc((size_t)3 * N_ * 4);
  float* er     = (float*)alloc((size_t)3 * N_ * 4);
  int*   counts = (int*)alloc((size_t)N_ * 4);
  // total = (2*8*768 + 6*8192 + 8192)*4 = 278528 B = 68 blocks * 256 * 16 B
  // ---- rest of scratch ----
  int*   offs   = (int*)alloc((size_t)(N_ + 1) * 4);
  int*   cursor = (int*)alloc((size_t)N_ * 4);
  int*   esrc   = (int*)alloc((size_t)NE_ * 4);

  // token pooling + W transposes + zero-fill in one dispatch (runs FIRST:
  // zeroes counts before k_count, el/er before gemm, avgp/qfp before avgqf)
  k_token_wt<<<N_ + NB_WT + NB_ZERO, 256, 0, stream>>>(features, token_spans, masks, selidx,
                                                       hA, Wl[0], Wl[1], Wl[2], Wt,
                                                       (int4*)avgp);

  // CSR build (edges constant across layers)
  k_count<<<(NE_ + 255) / 256, 256, 0, stream>>>(dst, counts, NE_);
  k_scan<<<1, 1024, 0, stream>>>(counts, offs, cursor);
  k_scatter<<<(NE_ + 255) / 256, 256, 0, stream>>>(dst, src, cursor, esrc, NE_);

  // 3 GAT layers: hA(bf16) -> z(hB,fp8)+el/er -> hA(bf16)
  for (int i = 0; i < 3; i++) {
    k_gemm_bf16<<<dim3(N_ / 128, H_ / 128), 256, 0, stream>>>(
        hA, Wt + (size_t)i * H_ * H_, hB, alv[i], arv[i],
        el + (size_t)i * N_, er + (size_t)i * N_);
    k_agg<<<N_ / 4, 256, 0, stream>>>(hB, el + (size_t)i * N_, er + (size_t)i * N_,
                                      offs, esrc, hA);
  }

  // doc-level reductions (avg + qf fused)
  k_avgqf<<<dim3(B_, 16), 192, 0, stream>>>(hA, features, masks, segment_ids, is_head,
                                            doc_spans, avgp, qfp);
  k_final<<<1, 512, 0, stream>>>(qfp, avgp, doc_spans, out);
}